// Round 7
// baseline (922.103 us; speedup 1.0000x reference)
//
#include <hip/hip_runtime.h>
#include <cstdint>
#include <cstddef>

typedef __bf16 bf16_t;
typedef __bf16 bf16x8 __attribute__((ext_vector_type(8)));
typedef __bf16 bf16x4 __attribute__((ext_vector_type(4)));
typedef float floatx4 __attribute__((ext_vector_type(4)));

// ---------------------------------------------------------------- helpers
__device__ __forceinline__ void async16(const bf16_t* g, bf16_t* l) {
  __builtin_amdgcn_global_load_lds(
      (const __attribute__((address_space(1))) unsigned int*)g,
      (__attribute__((address_space(3))) unsigned int*)l, 16, 0, 0);
}

// Barrier that drains ONLY lgkmcnt (LDS) — leaves prefetch global loads
// in flight across the barrier (compiler's __syncthreads drains vmcnt(0)).
__device__ __forceinline__ void barrier_lds() {
  asm volatile("s_waitcnt lgkmcnt(0)\n\ts_barrier" ::: "memory");
}

__device__ __forceinline__ float siluf(float x) { return x / (1.f + __expf(-x)); }

#define MFMA16(a, b, c) __builtin_amdgcn_mfma_f32_16x16x32_bf16(a, b, c, 0, 0, 0)
#define WAITV(n) asm volatile("s_waitcnt vmcnt(" #n ")" ::: "memory")
#define SBAR() asm volatile("s_barrier" ::: "memory")

// ---------------------------------------------------------------- fp32 -> bf16
__global__ __launch_bounds__(256) void k_cvt(const float* __restrict__ in,
                                             bf16_t* __restrict__ out, int n4) {
  int i = blockIdx.x * 256 + threadIdx.x;
  if (i >= n4) return;
  const float4 f = ((const float4*)in)[i];
  bf16x4 r;
  r[0] = (bf16_t)f.x; r[1] = (bf16_t)f.y; r[2] = (bf16_t)f.z; r[3] = (bf16_t)f.w;
  ((bf16x4*)out)[i] = r;
}

// W_b rows 0..31, W_a rows 32..63, zeros 64..127
__global__ __launch_bounds__(256) void k_build_wba(const float* __restrict__ wb,
                                                   const float* __restrict__ wa,
                                                   bf16_t* __restrict__ out) {
  int i = blockIdx.x * 256 + threadIdx.x;
  int e = i * 4;
  int row = e >> 11;
  int col = e & 2047;
  float4 f = make_float4(0.f, 0.f, 0.f, 0.f);
  if (row < 32)      f = *(const float4*)&wb[row * 2048 + col];
  else if (row < 64) f = *(const float4*)&wa[(row - 32) * 2048 + col];
  bf16x4 r;
  r[0] = (bf16_t)f.x; r[1] = (bf16_t)f.y; r[2] = (bf16_t)f.z; r[3] = (bf16_t)f.w;
  *(bf16x4*)&out[e] = r;
}

// ---------------------------------------------------------------- GEMM (m97-style)
// Kept for the small N=128 (ba) GEMM.
template<bool OUT_BF16>
__global__ __launch_bounds__(256) void gemm_bt(const bf16_t* __restrict__ A,
                                               const bf16_t* __restrict__ B,
                                               void* __restrict__ Cout,
                                               int M, int N, int K) {
  __shared__ __align__(16) bf16_t As[4096];
  __shared__ __align__(16) bf16_t Bs[4096];
  const int tid  = threadIdx.x;
  const int lane = tid & 63;
  const int wave = tid >> 6;
  const int quad = lane >> 4;
  const int l16  = lane & 15;
  const int wr   = (wave >> 1) * 64;
  const int wc   = (wave & 1) * 64;
  const int m0   = blockIdx.y * 128;
  const int n0   = blockIdx.x * 128;
  const int ra   = tid >> 2;
  const int ca   = (tid & 3) * 8;

  const bf16_t* gA = A + (size_t)(m0 + ra) * K + ca;
  const bf16_t* gB = B + (size_t)(n0 + ra) * K + ca;
  bf16_t* lA = &As[tid * 8];
  bf16_t* lB = &Bs[tid * 8];

  floatx4 acc[4][4] = {};

  for (int k0 = 0; k0 < K; k0 += 32) {
    __syncthreads();
    async16(gA + k0, lA);
    async16(gA + k0 + (size_t)64 * K, lA + 2048);
    async16(gB + k0, lB);
    async16(gB + k0 + (size_t)64 * K, lB + 2048);
    __syncthreads();
    bf16x8 af[4], bfr[4];
#pragma unroll
    for (int i = 0; i < 4; ++i) {
      af[i]  = *(const bf16x8*)&As[(wr + i * 16 + l16) * 32 + quad * 8];
      bfr[i] = *(const bf16x8*)&Bs[(wc + i * 16 + l16) * 32 + quad * 8];
    }
#pragma unroll
    for (int mi = 0; mi < 4; ++mi)
#pragma unroll
      for (int ni = 0; ni < 4; ++ni)
        acc[mi][ni] = MFMA16(af[mi], bfr[ni], acc[mi][ni]);
  }

#pragma unroll
  for (int mi = 0; mi < 4; ++mi) {
#pragma unroll
    for (int ni = 0; ni < 4; ++ni) {
      const int row = m0 + wr + mi * 16 + quad * 4;
      const int col = n0 + wc + ni * 16 + l16;
#pragma unroll
      for (int r = 0; r < 4; ++r) {
        if (OUT_BF16)
          ((bf16_t*)Cout)[(size_t)(row + r) * N + col] = (bf16_t)acc[mi][ni][r];
        else
          ((float*)Cout)[(size_t)(row + r) * N + col] = acc[mi][ni][r];
      }
    }
  }
}

// ---------------------------------------------------------------- 8-phase 256x256 GEMM (BK=64)
// Full T-stack: T1 XCD swizzle, T2 LDS swizzle, T3 8-phase, T4 counted vmcnt,
// T5 setprio. 512 thr = 8 waves (2M x 4N), per-wave C = 128x64.
// LDS: 2 dbuf x (A[256][64] + B[256][64]) = 128 KB. K-tile X in buf X&1.
// Per K-tile, 4 phases = C-quadrants (mh,nh): (0,0),(0,1),(1,0),(1,1);
// ds_reads/phase {12,4,8,0}, 16 MFMA/phase, 1 half-tile staged per phase:
//   P1: stage A(X+1).lo   P2: stage A(X+1).hi
//   P3: stage B(X+2).lo   P4: stage B(X+2).hi ; vmcnt(4)
// Swizzle: LDS[row][c8] = G[row][c8 ^ (row&7)]; source pre-swizzled (rule #21).
template<bool OUT_BF16>
__global__ __launch_bounds__(512, 1) void gemm8p(const bf16_t* __restrict__ A,
                                                 const bf16_t* __restrict__ B,
                                                 void* __restrict__ Cout,
                                                 int M, int N, int K) {
  extern __shared__ __align__(16) bf16_t sm[];
  const int tid  = threadIdx.x;
  const int lane = tid & 63;
  const int wave = tid >> 6;   // 0..7
  const int quad = lane >> 4;
  const int l16  = lane & 15;
  const int wm   = wave >> 2;  // M half (128 rows)
  const int wn   = wave & 3;   // N quarter (64 cols)

  // T1: bijective XCD swizzle (caller guarantees nwg % 8 == 0)
  const int gx  = (int)gridDim.x;
  const int nwg = gx * (int)gridDim.y;
  const int id  = (int)blockIdx.y * gx + (int)blockIdx.x;
  const int cpx = nwg >> 3;
  const int sw  = (id & 7) * cpx + (id >> 3);
  const int m0  = (sw / gx) * 256;
  const int n0  = (sw % gx) * 256;

  // staging: one half-tile = [128][64] bf16 = 16KB = 512 thr x 2 x 16B.
  const int rowg   = tid >> 3;
  const int colsrc = (tid & 7) ^ (rowg & 7);
  const bf16_t* gAs = A + (size_t)(m0 + rowg) * K + colsrc * 8;
  const bf16_t* gBs = B + (size_t)(n0 + rowg) * K + colsrc * 8;
  bf16_t* lds0 = sm + tid * 8;

#define STG_A8(u, kt, ht) {                                     \
    bf16_t* la = lds0 + (u) * 32768 + (ht) * 8192;              \
    const bf16_t* ga = gAs + (size_t)(ht) * 128 * K + (kt) * 64;\
    async16(ga, la); async16(ga + (size_t)64 * K, la + 4096); }
#define STG_B8(u, kt, ht) {                                     \
    bf16_t* lb = lds0 + (u) * 32768 + 16384 + (ht) * 8192;      \
    const bf16_t* gb = gBs + (size_t)(ht) * 128 * K + (kt) * 64;\
    async16(gb, lb); async16(gb + (size_t)64 * K, lb + 4096); }

  // fragment read constants (row&7 == l16&7 for all frag rows)
  const int x7  = l16 & 7;
  const int cA0 = ((quad + 0) ^ x7) * 8;  // kk=0 swizzled 8-elem slot
  const int cA1 = ((quad + 4) ^ x7) * 8;  // kk=1
  const int eA0 = (wm * 128 + l16) * 64;
  const int eB0 = 16384 + (wn * 64 + l16) * 64;

  floatx4 acc[8][4] = {};
  const int KT = K >> 6;  // BK=64; caller guarantees K%64==0, KT>=3

  // ---- prologue: A0.lo A0.hi B0.lo B0.hi B1.lo B1.hi (12 loads)
  STG_A8(0, 0, 0); STG_A8(0, 0, 1);
  STG_B8(0, 0, 0); STG_B8(0, 0, 1);
  STG_B8(1, 1, 0); STG_B8(1, 1, 1);
  WAITV(4);
  SBAR();

  bf16x8 af[4][2], bn0[2][2], bn1[2][2];
  for (int X = 0; X < KT; ++X) {
    const int c = X & 1;
    const bf16_t* sb = sm + c * 32768;

    // ---- P1: (mh0, nh0); read A-mh0 (8) + B-nh0 (4); stage A(X+1).lo
#pragma unroll
    for (int i = 0; i < 4; ++i) {
      af[i][0] = *(const bf16x8*)&sb[eA0 + i * 1024 + cA0];
      af[i][1] = *(const bf16x8*)&sb[eA0 + i * 1024 + cA1];
    }
#pragma unroll
    for (int j = 0; j < 2; ++j) {
      bn0[j][0] = *(const bf16x8*)&sb[eB0 + j * 1024 + cA0];
      bn0[j][1] = *(const bf16x8*)&sb[eB0 + j * 1024 + cA1];
    }
    if (X + 1 < KT) STG_A8(c ^ 1, X + 1, 0);
    SBAR();
    __builtin_amdgcn_s_setprio(1);
#pragma unroll
    for (int i = 0; i < 4; ++i)
#pragma unroll
      for (int j = 0; j < 2; ++j) {
        acc[i][j] = MFMA16(af[i][0], bn0[j][0], acc[i][j]);
        acc[i][j] = MFMA16(af[i][1], bn0[j][1], acc[i][j]);
      }
    __builtin_amdgcn_s_setprio(0);
    SBAR();

    // ---- P2: (mh0, nh1); read B-nh1 (4); stage A(X+1).hi
#pragma unroll
    for (int j = 0; j < 2; ++j) {
      bn1[j][0] = *(const bf16x8*)&sb[eB0 + (2 + j) * 1024 + cA0];
      bn1[j][1] = *(const bf16x8*)&sb[eB0 + (2 + j) * 1024 + cA1];
    }
    if (X + 1 < KT) STG_A8(c ^ 1, X + 1, 1);
    SBAR();
    __builtin_amdgcn_s_setprio(1);
#pragma unroll
    for (int i = 0; i < 4; ++i)
#pragma unroll
      for (int j = 0; j < 2; ++j) {
        acc[i][2 + j] = MFMA16(af[i][0], bn1[j][0], acc[i][2 + j]);
        acc[i][2 + j] = MFMA16(af[i][1], bn1[j][1], acc[i][2 + j]);
      }
    __builtin_amdgcn_s_setprio(0);
    SBAR();

    // ---- P3: (mh1, nh0); read A-mh1 (8); stage B(X+2).lo
#pragma unroll
    for (int i = 0; i < 4; ++i) {
      af[i][0] = *(const bf16x8*)&sb[eA0 + (4 + i) * 1024 + cA0];
      af[i][1] = *(const bf16x8*)&sb[eA0 + (4 + i) * 1024 + cA1];
    }
    if (X + 2 < KT) STG_B8(c, X + 2, 0);
    SBAR();
    __builtin_amdgcn_s_setprio(1);
#pragma unroll
    for (int i = 0; i < 4; ++i)
#pragma unroll
      for (int j = 0; j < 2; ++j) {
        acc[4 + i][j] = MFMA16(af[i][0], bn0[j][0], acc[4 + i][j]);
        acc[4 + i][j] = MFMA16(af[i][1], bn0[j][1], acc[4 + i][j]);
      }
    __builtin_amdgcn_s_setprio(0);
    SBAR();

    // ---- P4: (mh1, nh1); stage B(X+2).hi; counted vmcnt
    if (X + 2 < KT) { STG_B8(c, X + 2, 1); WAITV(4); }
    else            { WAITV(0); }
    SBAR();
    __builtin_amdgcn_s_setprio(1);
#pragma unroll
    for (int i = 0; i < 4; ++i)
#pragma unroll
      for (int j = 0; j < 2; ++j) {
        acc[4 + i][2 + j] = MFMA16(af[i][0], bn1[j][0], acc[4 + i][2 + j]);
        acc[4 + i][2 + j] = MFMA16(af[i][1], bn1[j][1], acc[4 + i][2 + j]);
      }
    __builtin_amdgcn_s_setprio(0);
    SBAR();
  }
#undef STG_A8
#undef STG_B8

  // ---- epilogue (proven C/D mapping)
#pragma unroll
  for (int mi = 0; mi < 8; ++mi) {
#pragma unroll
    for (int ni = 0; ni < 4; ++ni) {
      const int row = m0 + wm * 128 + mi * 16 + quad * 4;
      const int col = n0 + wn * 64 + ni * 16 + l16;
#pragma unroll
      for (int r = 0; r < 4; ++r) {
        if (OUT_BF16)
          ((bf16_t*)Cout)[(size_t)(row + r) * N + col] = (bf16_t)acc[mi][ni][r];
        else
          ((float*)Cout)[(size_t)(row + r) * N + col] = acc[mi][ni][r];
      }
    }
  }
}

// ---------------------------------------------------------------- big-tile deep-pipelined GEMM
// MH=1: BM=128 (N=2048 out-GEMM: grid (8,32)=256 blocks -> full GPU),
// 2-phase, per-wave loads/K-tile = 3 -> vmcnt 6/3/0; ring 4 x 24KB = 96KB LDS.
template<int MH, bool OUT_BF16>
__global__ __launch_bounds__(512, 1) void gemm_big(const bf16_t* __restrict__ A,
                                                   const bf16_t* __restrict__ B,
                                                   void* __restrict__ Cout,
                                                   int M, int N, int K) {
  extern __shared__ __align__(16) bf16_t sm[];
  constexpr int BM    = MH * 128;
  constexpr int MFRAG = MH * 4;
  constexpr int HF    = MFRAG / 2;
  constexpr int BUFE  = MH * 4096 + 8192;  // elems per ring buffer (A + B)
  const int tid  = threadIdx.x;
  const int lane = tid & 63;
  const int wave = tid >> 6;   // 0..7
  const int quad = lane >> 4;
  const int l16  = lane & 15;
  const int wm   = wave >> 2;  // 0..1  M half
  const int wn   = wave & 3;   // 0..3  N quarter (64 cols)

  // bijective XCD swizzle (caller guarantees nwg % 8 == 0)
  const int gx  = (int)gridDim.x;
  const int nwg = gx * (int)gridDim.y;
  const int id  = (int)blockIdx.y * gx + (int)blockIdx.x;
  const int cpx = nwg >> 3;
  const int sw  = (id & 7) * cpx + (id >> 3);
  const int m0  = (sw / gx) * BM;
  const int n0  = (sw % gx) * 256;

  // ---- staging addresses (each issue: 64 lanes x 16B = 16 rows x 64B)
  const int lr    = lane >> 2;                       // row within issue
  const int lslot = (lane & 3) ^ ((lane >> 3) & 3);  // pre-swizzled 16B slot
  const bf16_t* gA = A + (size_t)(m0 + wave * (MH * 16) + lr) * K + lslot * 8;
  const bf16_t* gB = B + (size_t)(n0 + wave * 32 + lr) * K + lslot * 8;
  const int ldsA0 = wave * (MH * 512) + lane * 8;
  const int ldsB0 = MH * 4096 + wave * 1024 + lane * 8;

#define STG_A(u, kt) {                                          \
    bf16_t* la = sm + (u) * BUFE + ldsA0;                       \
    const bf16_t* ga = gA + (size_t)(kt) * 32;                  \
    async16(ga, la);                                            \
    if constexpr (MH == 2) async16(ga + (size_t)16 * K, la + 512); }
#define STG_B(u, kt) {                                          \
    bf16_t* lb = sm + (u) * BUFE + ldsB0;                       \
    const bf16_t* gb = gB + (size_t)(kt) * 32;                  \
    async16(gb, lb);                                            \
    async16(gb + (size_t)16 * K, lb + 512); }

  int offA[MFRAG], offB[4];
#pragma unroll
  for (int i = 0; i < MFRAG; ++i) {
    int ra = wm * (MFRAG * 16) + i * 16 + l16;
    offA[i] = (ra * 32 + quad * 8) ^ (((ra >> 1) & 3) << 3);
  }
#pragma unroll
  for (int i = 0; i < 4; ++i) {
    int rb = wn * 64 + i * 16 + l16;
    offB[i] = MH * 4096 + ((rb * 32 + quad * 8) ^ (((rb >> 1) & 3) << 3));
  }

  floatx4 acc[MFRAG][4] = {};
  const int KT = K >> 5;  // caller guarantees KT >= 4

  STG_A(0, 0); STG_B(0, 0);
  STG_A(1, 1); STG_B(1, 1);
  STG_A(2, 2); STG_B(2, 2);
  if constexpr (MH == 2) WAITV(8); else WAITV(6);
  SBAR();

  for (int U = 0; U < KT; ++U) {
    const int bu = U & 3;
    const bf16_t* sb = sm + bu * BUFE;
    const int un = U + 3;
    const int tu = un & 3;
    bf16x8 af[HF], bfr[4];

    // ---- phase 0: M lower half; stage A(U+3)
#pragma unroll
    for (int i = 0; i < HF; ++i) af[i] = *(const bf16x8*)&sb[offA[i]];
#pragma unroll
    for (int i = 0; i < 4; ++i) bfr[i] = *(const bf16x8*)&sb[offB[i]];
    if (un < KT) STG_A(tu, un);
    SBAR();
    __builtin_amdgcn_s_setprio(1);
#pragma unroll
    for (int mi = 0; mi < HF; ++mi)
#pragma unroll
      for (int ni = 0; ni < 4; ++ni)
        acc[mi][ni] = MFMA16(af[mi], bfr[ni], acc[mi][ni]);
    __builtin_amdgcn_s_setprio(0);
    SBAR();

    // ---- phase 1: M upper half; stage B(U+3); counted vmcnt
#pragma unroll
    for (int i = 0; i < HF; ++i) af[i] = *(const bf16x8*)&sb[offA[HF + i]];
    if (un < KT) STG_B(tu, un);
    if (un < KT)         { if constexpr (MH == 2) WAITV(8); else WAITV(6); }
    else if (U + 2 < KT) { if constexpr (MH == 2) WAITV(4); else WAITV(3); }
    else                 WAITV(0);
    SBAR();
    __builtin_amdgcn_s_setprio(1);
#pragma unroll
    for (int mi = 0; mi < HF; ++mi)
#pragma unroll
      for (int ni = 0; ni < 4; ++ni)
        acc[HF + mi][ni] = MFMA16(af[mi], bfr[ni], acc[HF + mi][ni]);
    __builtin_amdgcn_s_setprio(0);
    SBAR();
  }
#undef STG_A
#undef STG_B

#pragma unroll
  for (int mi = 0; mi < MFRAG; ++mi) {
#pragma unroll
    for (int ni = 0; ni < 4; ++ni) {
      const int row = m0 + wm * (MFRAG * 16) + mi * 16 + quad * 4;
      const int col = n0 + wn * 64 + ni * 16 + l16;
#pragma unroll
      for (int r = 0; r < 4; ++r) {
        if (OUT_BF16)
          ((bf16_t*)Cout)[(size_t)(row + r) * N + col] = (bf16_t)acc[mi][ni][r];
        else
          ((float*)Cout)[(size_t)(row + r) * N + col] = acc[mi][ni][r];
      }
    }
  }
}

// ---------------------------------------------------------------- beta / g ([h][t] layout)
__global__ __launch_bounds__(256) void k_betag(const float* __restrict__ cba,
                                               const float* __restrict__ A_log,
                                               const float* __restrict__ dtb,
                                               float* __restrict__ beta_t,
                                               float* __restrict__ g_t) {
  int i = blockIdx.x * 256 + threadIdx.x;  // T*32
  int t = i >> 5, h = i & 31;
  float b = cba[t * 128 + h];
  float a = cba[t * 128 + 32 + h];
  beta_t[h * 4096 + t] = 1.f / (1.f + __expf(-b));
  float x = a + dtb[h];
  float sp = (x > 20.f) ? x : log1pf(__expf(x));
  g_t[h * 4096 + t] = -__expf(A_log[h]) * sp;
}

// ---------------------------------------------------------------- conv4 + silu + l2norm
__global__ __launch_bounds__(64) void k_conv(const bf16_t* __restrict__ mixed,
                                             const float* __restrict__ cw,
                                             bf16_t* __restrict__ qo,
                                             bf16_t* __restrict__ ko,
                                             bf16_t* __restrict__ vo) {
  const int grp = blockIdx.x;
  const int t0 = blockIdx.y * 8;
  const int l = threadIdx.x;
  const int c0 = grp * 128 + l;
  const int c1 = c0 + 64;
  const float4 w0 = *(const float4*)&cw[c0 * 4];
  const float4 w1 = *(const float4*)&cw[c1 * 4];
  float h0[3], h1[3];
#pragma unroll
  for (int j = 0; j < 3; ++j) {
    int tt = t0 - 3 + j;
    h0[j] = (tt >= 0) ? (float)mixed[(size_t)tt * 8192 + c0] : 0.f;
    h1[j] = (tt >= 0) ? (float)mixed[(size_t)tt * 8192 + c1] : 0.f;
  }
#pragma unroll
  for (int i = 0; i < 8; ++i) {
    const int t = t0 + i;
    float x0 = (float)mixed[(size_t)t * 8192 + c0];
    float x1 = (float)mixed[(size_t)t * 8192 + c1];
    float a0 = w0.x * h0[0] + w0.y * h0[1] + w0.z * h0[2] + w0.w * x0;
    float a1 = w1.x * h1[0] + w1.y * h1[1] + w1.z * h1[2] + w1.w * x1;
    h0[0] = h0[1]; h0[1] = h0[2]; h0[2] = x0;
    h1[0] = h1[1]; h1[1] = h1[2]; h1[2] = x1;
    float v0 = siluf(a0), v1 = siluf(a1);
    if (grp < 32) {
      float s = v0 * v0 + v1 * v1;
#pragma unroll
      for (int m = 1; m < 64; m <<= 1) s += __shfl_xor(s, m);
      float r = rsqrtf(s + 1e-6f);
      if (grp < 16) {
        bf16_t* q = qo + ((size_t)t * 16 + grp) * 128;
        q[l]      = (bf16_t)(v0 * r * 0.08838834764831845f);  // DK^-0.5 folded
        q[l + 64] = (bf16_t)(v1 * r * 0.08838834764831845f);
      } else {
        bf16_t* k = ko + ((size_t)t * 16 + grp - 16) * 128;
        k[l]      = (bf16_t)(v0 * r);
        k[l + 64] = (bf16_t)(v1 * r);
      }
    } else {
      bf16_t* v = vo + ((size_t)t * 32 + grp - 32) * 128;
      v[l]      = (bf16_t)v0;
      v[l + 64] = (bf16_t)v1;
    }
  }
}

// ---------------------------------------------------------------- k_prep
__global__ __launch_bounds__(256, 2) void k_prep(
    const bf16_t* __restrict__ qg, const bf16_t* __restrict__ kg,
    const bf16_t* __restrict__ vg,
    const float* __restrict__ bb_t, const float* __restrict__ gb_t,
    bf16_t* __restrict__ Vt, bf16_t* __restrict__ Wlo, bf16_t* __restrict__ Whi,
    bf16_t* __restrict__ Mout, bf16_t* __restrict__ kt, float* __restrict__ smalls) {
  const int c = blockIdx.x >> 5;
  const int h = blockIdx.x & 31;
  const int kh = h >> 1;
  const int t0 = c * 64;
  const int tid = threadIdx.x, lane = tid & 63, wave = tid >> 6;
  const int quad = lane >> 4, l16 = lane & 15;

  __shared__ __align__(16) bf16_t lsKQ[2][64][136];
  __shared__ float lsC[64][68];
  __shared__ float lsG[64], lsA[64], lsSc[64], lsBeta[64];

  {
    const int r = tid >> 2, s0 = (tid & 3) * 32;
    const bf16_t* kr = kg + ((size_t)(t0 + r) * 16 + kh) * 128 + s0;
    const bf16_t* qr = qg + ((size_t)(t0 + r) * 16 + kh) * 128 + s0;
#pragma unroll
    for (int j = 0; j < 4; ++j) {
      *(uint4*)&lsKQ[0][r][s0 + j * 8] = *(const uint4*)&kr[j * 8];
      *(uint4*)&lsKQ[1][r][s0 + j * 8] = *(const uint4*)&qr[j * 8];
    }
  }
  if (wave == 0) {
    float gv = gb_t[(size_t)h * 4096 + t0 + lane];
#pragma unroll
    for (int off = 1; off < 64; off <<= 1) {
      float n = __shfl_up(gv, off);
      if (lane >= off) gv += n;
    }
    float GL = __shfl(gv, 63);
    lsG[lane] = gv;
    lsA[lane] = __expf(gv);
    lsSc[lane] = __expf(GL - gv);
    lsBeta[lane] = bb_t[(size_t)h * 4096 + t0 + lane];
  }
  __syncthreads();

  const int mr = (wave >> 1) * 32, nr = (wave & 1) * 32;
  floatx4 ak[2][2] = {}, aq[2][2] = {};
  if (wave != 1) {
#pragma unroll
    for (int ks = 0; ks < 4; ++ks) {
      bf16x8 yf[2], xk[2], xq[2];
#pragma unroll
      for (int i = 0; i < 2; ++i) {
        yf[i] = *(const bf16x8*)&lsKQ[0][nr + i * 16 + l16][ks * 32 + quad * 8];
        xk[i] = *(const bf16x8*)&lsKQ[0][mr + i * 16 + l16][ks * 32 + quad * 8];
        xq[i] = *(const bf16x8*)&lsKQ[1][mr + i * 16 + l16][ks * 32 + quad * 8];
      }
#pragma unroll
      for (int i = 0; i < 2; ++i)
#pragma unroll
        for (int j = 0; j < 2; ++j) {
          ak[i][j] = MFMA16(xk[i], yf[j], ak[i][j]);
          aq[i][j] = MFMA16(xq[i], yf[j], aq[i][j]);
        }
    }
  }
  bf16_t* Mb = Mout + (size_t)(h * 64 + c) * 4096;
#pragma unroll
  for (int i = 0; i < 2; ++i)
#pragma unroll
    for (int j = 0; j < 2; ++j)
#pragma unroll
      for (int r = 0; r < 4; ++r) {
        int t = mr + i * 16 + quad * 4 + r;
        int s = nr + j * 16 + l16;
        float e = __expf(lsG[t] - lsG[s]);
        float cv = (s < t) ? lsBeta[t] * e * ak[i][j][r] : 0.f;
        float mv = (s <= t) ? e * aq[i][j][r] : 0.f;
        if (wave != 1) lsC[t][s] = cv;
        Mb[t * 64 + s] = (bf16_t)mv;
      }
  __syncthreads();

  // forward substitution: thread <-> column. cols 0..127: V, 128..255: W-rhs
  const int col = tid & 127;
  const bool isW = tid >= 128;
  float vals[64];
#pragma unroll
  for (int t = 0; t < 64; ++t) {
    float b;
    if (!isW) b = (float)vg[((size_t)(t0 + t) * 32 + h) * 128 + col];
    else      b = lsA[t] * (float)lsKQ[0][t][col];
    vals[t] = lsBeta[t] * b;
  }
#pragma unroll
  for (int t = 1; t < 64; ++t) {
    float acc = vals[t];
#pragma unroll
    for (int s4 = 0; s4 <= (t - 1) >> 2; ++s4) {
      float4 cv = *(const float4*)&lsC[t][s4 * 4];
      acc -= cv.x * vals[s4 * 4 + 0];
      acc -= cv.y * vals[s4 * 4 + 1];
      acc -= cv.z * vals[s4 * 4 + 2];
      acc -= cv.w * vals[s4 * 4 + 3];
    }
    vals[t] = acc;
  }

  // V columns: direct transposed write (VtT[dv][t], contiguous in t)
  if (!isW) {
    bf16_t* vd = Vt + (size_t)(h * 64 + c) * 8192 + (size_t)col * 64;
#pragma unroll
    for (int j = 0; j < 16; ++j) {
      bf16x4 p;
      p[0] = (bf16_t)vals[j * 4 + 0];
      p[1] = (bf16_t)vals[j * 4 + 1];
      p[2] = (bf16_t)vals[j * 4 + 2];
      p[3] = (bf16_t)vals[j * 4 + 3];
      *(bf16x4*)&vd[j * 4] = p;
    }
  } else {
#pragma unroll
    for (int t = 0; t < 64; ++t) vals[t] = -vals[t];  // W' = -W
  }

  // K^T for the chain
  if ((h & 1) == 0) {
    const int dk = tid >> 1, sh = (tid & 1) * 32;
    bf16_t* kd = kt + (size_t)(c * 16 + kh) * 8192 + (size_t)dk * 64 + sh;
#pragma unroll
    for (int j4 = 0; j4 < 4; ++j4) {
      bf16x8 v;
#pragma unroll
      for (int e = 0; e < 8; ++e) v[e] = lsKQ[0][sh + j4 * 8 + e][dk];
      *(bf16x8*)&kd[j4 * 8] = v;
    }
  }
  if (tid < 64) {
    float* sm = smalls + (size_t)(h * 64 + c) * 128;
    sm[tid] = lsA[tid];
    sm[64 + tid] = lsSc[tid];
  }
  __syncthreads();

  // transpose W half via LDS (overlay lsKQ), pitch 272
  bf16_t* lsT = &lsKQ[0][0][0];
  if (isW) {
#pragma unroll
    for (int t = 0; t < 64; ++t) lsT[t * 272 + tid] = (bf16_t)vals[t];
  }
  __syncthreads();

  // cooperative vectorized W' write: [t][dk 128]
  {
    const int r = tid >> 2, part = tid & 3;
    const bf16_t* src = &lsT[r * 272 + 128 + part * 32];
    bf16_t* Wb = (h < 16 ? Wlo : Whi) + (size_t)((h & 15) * 64 + c) * 8192 + r * 128 + part * 32;
#pragma unroll
    for (int j = 0; j < 4; ++j)
      *(uint4*)&Wb[j * 8] = *(const uint4*)&src[j * 8];
  }
}

// ---------------------------------------------------------------- k_chain (paired dv-eighths)
// grid = 128: blockIdx = qq*32 + h, qq = dv-QUARTER. 512 threads = TWO
// independent 4-wave groups; group g handles dv-eighth dv0 = qq*32 + g*16.
// Rationale (R6): with 1 wave/SIMD the chunk loop is ~85% stall (exposed
// LDS/MFMA latency + barrier drains). R2 showed splitting ONE recurrence
// across more lockstep waves regresses (per-wave ILP halves). Instead keep
// the proven per-wave structure and co-locate TWO recurrences per block:
// 2 waves/SIMD from DIFFERENT groups -> one issues while the other stalls
// (m114 overlap). Both groups run identical loop cadence so the shared
// block-wide barriers are hit uniformly (no divergent-barrier hazard); the
// barrier is merely stronger than each group needs. Groups read identical
// W/Q/K/M addresses (g only affects V/o) -> L1/L2 hits, no extra HBM.
// Per chunk per group: X = Vt + W'.S ; o = A*(Q.S) + M.X ; S' = aL*S + K^T.(sc*X)
__global__ __launch_bounds__(512, 1) void k_chain(
    const bf16_t* __restrict__ qg, const bf16_t* __restrict__ VtT,
    const bf16_t* __restrict__ Wlo, const bf16_t* __restrict__ Whi,
    const bf16_t* __restrict__ Mg, const bf16_t* __restrict__ ktg,
    const float* __restrict__ smalls, bf16_t* __restrict__ o) {
  const int h = blockIdx.x & 31;
  const int qq = blockIdx.x >> 5;          // dv-quarter 0..3
  const int kh = h >> 1;
  const int tid = threadIdx.x;
  const int g = tid >> 8;                  // group 0/1
  const int t2 = tid & 255;
  const int lane = t2 & 63, wave = t2 >> 6;
  const int quad = lane >> 4, l16 = lane & 15;
  const int trow = wave * 16 + quad * 4;
  const int dv0 = qq * 32 + g * 16;

  __shared__ __align__(16) bf16_t lsXT[2][16][72];
  __shared__ __align__(16) bf16_t lsXbT[2][16][72];
  __shared__ __align__(16) bf16_t lsS[2][16][136];

  const bf16_t* Wbase = (h < 16 ? Wlo : Whi) + (size_t)(h & 15) * 64 * 8192;
  const bf16_t* Vbase = VtT + (size_t)h * 64 * 8192;
  const bf16_t* Mbase = Mg + (size_t)h * 64 * 4096;
  const float*  Sbase = smalls + (size_t)h * 64 * 128;

  // running per-wave pointers (advanced by constant strides per chunk)
  const bf16_t* pW = Wbase + (size_t)(wave * 16 + l16) * 128 + quad * 8;
  const bf16_t* pQ = qg + ((size_t)(wave * 16 + l16) * 16 + kh) * 128 + quad * 8;
  const bf16_t* pK = ktg + (size_t)kh * 8192 + (size_t)(wave * 16 + l16) * 64 + quad * 8;
  const bf16_t* pM = Mbase + (size_t)(wave * 16 + l16) * 64 + quad * 8;
  const bf16_t* pV = Vbase + (size_t)(dv0 + l16) * 64 + trow;
  const float*  pS = Sbase;

  floatx4 sacc[2] = {};
  for (int i = t2; i < 16 * 136; i += 256) (&lsS[g][0][0])[i] = (bf16_t)0.f;

  bf16x8 nW[4], nQ[4], nK[4], nM[2];
  bf16x4 nV;
  float4 nA, nSc;
  float nAL;
  {
#pragma unroll
    for (int ks = 0; ks < 4; ++ks) {
      nW[ks] = *(const bf16x8*)&pW[ks * 32];
      nQ[ks] = *(const bf16x8*)&pQ[ks * 32];
    }
    nK[0] = *(const bf16x8*)&pK[0];
    nK[1] = *(const bf16x8*)&pK[32];
    nK[2] = *(const bf16x8*)&pK[4096];
    nK[3] = *(const bf16x8*)&pK[4096 + 32];
    nM[0] = *(const bf16x8*)&pM[0];
    nM[1] = *(const bf16x8*)&pM[32];
    nV = *(const bf16x4*)&pV[0];
    nA  = *(const float4*)&pS[trow];
    nSc = *(const float4*)&pS[64 + trow];
    nAL = pS[63];
    pW += 8192; pQ += 131072; pK += 131072; pM += 4096; pV += 8192; pS += 128;
  }
  __syncthreads();

  for (int cc = 0; cc < 64; ++cc) {
    const int t0 = cc * 64;
    bf16x8 cW[4], cQ[4], cK[4], cM[2];
    float cV[4];
    float4 cA = nA, cSc = nSc;
    float cAL = nAL;
#pragma unroll
    for (int ks = 0; ks < 4; ++ks) { cW[ks] = nW[ks]; cQ[ks] = nQ[ks]; cK[ks] = nK[ks]; }
    cM[0] = nM[0]; cM[1] = nM[1];
#pragma unroll
    for (int r = 0; r < 4; ++r) cV[r] = (float)nV[r];

    if (cc + 1 < 64) {
#pragma unroll
      for (int ks = 0; ks < 4; ++ks) {
        nW[ks] = *(const bf16x8*)&pW[ks * 32];
        nQ[ks] = *(const bf16x8*)&pQ[ks * 32];
      }
      nK[0] = *(const bf16x8*)&pK[0];
      nK[1] = *(const bf16x8*)&pK[32];
      nK[2] = *(const bf16x8*)&pK[4096];
      nK[3] = *(const bf16x8*)&pK[4096 + 32];
      nM[0] = *(const bf16x8*)&pM[0];
      nM[1] = *(const bf16x8*)&pM[32];
      nV = *(const bf16x4*)&pV[0];
      nA  = *(const float4*)&pS[trow];
      nSc = *(const float4*)&pS[64 + trow];
      nAL = pS[63];
      pW += 8192; pQ += 131072; pK += 131072; pM += 4096; pV += 8192; pS += 128;
    }

    // ---- P0: X = Vt + W'.S  (bS kept in regs)
    bf16x8 bS[4];
#pragma unroll
    for (int ks = 0; ks < 4; ++ks)
      bS[ks] = *(const bf16x8*)&lsS[g][l16][ks * 32 + quad * 8];
    floatx4 xacc;
#pragma unroll
    for (int r = 0; r < 4; ++r) xacc[r] = cV[r];
#pragma unroll
    for (int ks = 0; ks < 4; ++ks)
      xacc = MFMA16(cW[ks], bS[ks], xacc);
    {
      bf16x4 px, pb;
#pragma unroll
      for (int r = 0; r < 4; ++r) {
        px[r] = (bf16_t)xacc[r];
        pb[r] = (bf16_t)(xacc[r] * ((const float*)&cSc)[r]);
      }
      *(bf16x4*)&lsXT[g][l16][trow] = px;
      *(bf16x4*)&lsXbT[g][l16][trow] = pb;
    }
    // ---- independent reg-only work (hides the ds_write drain before B1):
    floatx4 qacc = {};
#pragma unroll
    for (int ks = 0; ks < 4; ++ks)
      qacc = MFMA16(cQ[ks], bS[ks], qacc);
#pragma unroll
    for (int r = 0; r < 4; ++r) qacc[r] *= ((const float*)&cA)[r];
#pragma unroll
    for (int mh = 0; mh < 2; ++mh)
#pragma unroll
      for (int r = 0; r < 4; ++r) sacc[mh][r] *= cAL;
    barrier_lds();  // B1: X ready (both groups); all lsS reads done

    // ---- P1 (short): o += M.X ; store o
#pragma unroll
    for (int ks = 0; ks < 2; ++ks) {
      bf16x8 bX = *(const bf16x8*)&lsXT[g][l16][ks * 32 + quad * 8];
      qacc = MFMA16(cM[ks], bX, qacc);
    }
#pragma unroll
    for (int r = 0; r < 4; ++r)
      o[((size_t)(t0 + trow + r) * 32 + h) * 128 + dv0 + l16] = (bf16_t)qacc[r];

    // ---- S' = aL*S + K^T.(sc*X)
#pragma unroll
    for (int ks = 0; ks < 2; ++ks) {
      bf16x8 bXb = *(const bf16x8*)&lsXbT[g][l16][ks * 32 + quad * 8];
#pragma unroll
      for (int mh = 0; mh < 2; ++mh)
        sacc[mh] = MFMA16(cK[mh * 2 + ks], bXb, sacc[mh]);
    }
    // ---- P2: refresh bf16 state (safe: all lsS reads happened before B1)
#pragma unroll
    for (int mh = 0; mh < 2; ++mh) {
      bf16x4 ps;
#pragma unroll
      for (int r = 0; r < 4; ++r) ps[r] = (bf16_t)sacc[mh][r];
      *(bf16x4*)&lsS[g][l16][(wave + 4 * mh) * 16 + quad * 4] = ps;
    }
    barrier_lds();  // B2: S visible; lsXT/lsXbT reads done before next P0 write
  }
}

// ---------------------------------------------------------------- RMSNorm * silu(z)
__global__ __launch_bounds__(256) void k_gate(const bf16_t* __restrict__ o,
                                              const bf16_t* __restrict__ z,
                                              const float* __restrict__ nw,
                                              bf16_t* __restrict__ y) {
  const int row = blockIdx.x * 4 + (threadIdx.x >> 6);  // t*32+h
  const int l = threadIdx.x & 63;
  const bf16_t* orow = o + (size_t)row * 128;
  float o0 = (float)orow[l], o1 = (float)orow[l + 64];
  float s = o0 * o0 + o1 * o1;
#pragma unroll
  for (int m = 1; m < 64; m <<= 1) s += __shfl_xor(s, m);
  float r = rsqrtf(s * (1.f / 128.f) + 1e-6f);
  const bf16_t* zrow = z + (size_t)row * 128;
  float z0 = (float)zrow[l], z1 = (float)zrow[l + 64];
  bf16_t* yrow = y + (size_t)row * 128;
  yrow[l]      = (bf16_t)(o0 * r * nw[l] * siluf(z0));
  yrow[l + 64] = (bf16_t)(o1 * r * nw[l + 64] * siluf(z1));
}

// ---------------------------------------------------------------- launch
extern "C" void kernel_launch(void* const* d_in, const int* in_sizes, int n_in,
                              void* d_out, int out_size, void* d_ws, size_t ws_size,
                              hipStream_t stream) {
  const float* hidden = (const float*)d_in[0];
  const float* W_qkv  = (const float*)d_in[1];
  const float* W_z    = (const float*)d_in[2];
  const float* W_b    = (const float*)d_in[3];
  const float* W_a    = (const float*)d_in[4];
  const float* conv_w = (const float*)d_in[5];
  const float* dt_b   = (const float*)d_in[6];
  const float* A_log  = (const float*)d_in[7];
  const float* norm_w = (const float*)d_in[8];
  const float* W_out  = (const float*)d_in[9];
  float* out = (float*)d_out;

  static int gemm_attr_done = 0;
  if (!gemm_attr_done) {
    hipFuncSetAttribute(reinterpret_cast<const void*>(&gemm8p<true>),
                        hipFuncAttributeMaxDynamicSharedMemorySize, 131072);
    hipFuncSetAttribute(reinterpret_cast<const void*>(&gemm_big<1, false>),
                        hipFuncAttributeMaxDynamicSharedMemorySize, 98304);
    gemm_attr_done = 1;
  }

  char* w = (char*)d_ws;
  const size_t MB = 1024 * 1024;
  bf16_t* hs    = (bf16_t*)(w + 0 * MB);     // 16MB; after ba-GEMM -> W_lo
  bf16_t* Wlo   = hs;
  bf16_t* wqkv  = (bf16_t*)(w + 16 * MB);    // 32MB; -> VtT (prep) -> ybuf (gate)
  bf16_t* Vtb   = wqkv;
  bf16_t* ybuf  = wqkv;
  bf16_t* wz    = (bf16_t*)(w + 48 * MB);    // 16MB; -> W_hi
  bf16_t* Whi   = wz;
  bf16_t* wout  = (bf16_t*)(w + 64 * MB);    // 16MB (live till end)
  bf16_t* wba   = (bf16_t*)(w + 80 * MB);    // 0.5MB
  bf16_t* mixed = (bf16_t*)(w + 81 * MB);    // 64MB (qkv out); after conv:
  bf16_t* obuf  = mixed;                     //   [obuf bf16 32MB @81]
  bf16_t* Mbuf  = (bf16_t*)(w + 113 * MB);   //   [M 16MB @113]
  bf16_t* ktb   = (bf16_t*)(w + 129 * MB);   //   [K^T 16MB @129]
  bf16_t* zbuf  = (bf16_t*)(w + 145 * MB);   // 32MB
  float*  cba   = (float*)(w + 177 * MB);    // 2MB; after betag -> smalls (1MB)
  float*  smalls= cba;
  bf16_t* qb    = (bf16_t*)(w + 179 * MB);   // 16MB
  bf16_t* kb    = (bf16_t*)(w + 195 * MB);   // 16MB
  bf16_t* vb    = (bf16_t*)(w + 211 * MB);   // 32MB
  float*  betab = (float*)(w + 243 * MB);    // 0.5MB [h][t]
  float*  gbuf  = (float*)(w + 243 * MB + 512 * 1024);  // 0.5MB [h][t]

  k_cvt<<<8192, 256, 0, stream>>>(hidden, hs, 2097152);
  k_cvt<<<16384, 256, 0, stream>>>(W_qkv, wqkv, 4194304);
  k_cvt<<<8192, 256, 0, stream>>>(W_z, wz, 2097152);
  k_cvt<<<8192, 256, 0, stream>>>(W_out, wout, 2097152);
  k_build_wba<<<256, 256, 0, stream>>>(W_b, W_a, wba);

  // 8-phase BK=64 pipeline for the two big GEMMs (grid %8==0, K%64==0)
  gemm8p<true><<<dim3(32, 16), 512, 131072, stream>>>(hs, wqkv, mixed, 4096, 8192, 2048);
  gemm8p<true><<<dim3(16, 16), 512, 131072, stream>>>(hs, wz, zbuf, 4096, 4096, 2048);
  gemm_bt<false><<<dim3(1, 32), 256, 0, stream>>>(hs, wba, cba, 4096, 128, 2048);
  k_betag<<<512, 256, 0, stream>>>(cba, A_log, dt_b, betab, gbuf);

  k_conv<<<dim3(64, 512), 64, 0, stream>>>(mixed, conv_w, qb, kb, vb);

  k_prep<<<2048, 256, 0, stream>>>(qb, kb, vb, betab, gbuf,
                                   Vtb, Wlo, Whi, Mbuf, ktb, smalls);
  // paired dv-eighths: 128 blocks x 512 thr (2 groups of 4 waves -> 2 waves/SIMD)
  k_chain<<<128, 512, 0, stream>>>(qb, Vtb, Wlo, Whi, Mbuf, ktb, smalls, obuf);

  k_gate<<<32768, 256, 0, stream>>>(obuf, zbuf, norm_w, ybuf);
  // out-GEMM: 128x256 tile -> grid (8,32)=256 blocks (%8==0), full GPU. K=4096.
  gemm_big<1, false><<<dim3(8, 32), 512, 98304, stream>>>(ybuf, wout, out, 4096, 2048, 4096);
}

// Round 8
// 816.831 us; speedup vs baseline: 1.1289x; 1.1289x over previous
//
#include <hip/hip_runtime.h>
#include <cstdint>
#include <cstddef>

typedef __bf16 bf16_t;
typedef __bf16 bf16x8 __attribute__((ext_vector_type(8)));
typedef __bf16 bf16x4 __attribute__((ext_vector_type(4)));
typedef float floatx4 __attribute__((ext_vector_type(4)));

// ---------------------------------------------------------------- helpers
__device__ __forceinline__ void async16(const bf16_t* g, bf16_t* l) {
  __builtin_amdgcn_global_load_lds(
      (const __attribute__((address_space(1))) unsigned int*)g,
      (__attribute__((address_space(3))) unsigned int*)l, 16, 0, 0);
}

// Barrier that drains ONLY lgkmcnt (LDS) — leaves prefetch global loads
// in flight across the barrier (compiler's __syncthreads drains vmcnt(0)).
__device__ __forceinline__ void barrier_lds() {
  asm volatile("s_waitcnt lgkmcnt(0)\n\ts_barrier" ::: "memory");
}

__device__ __forceinline__ float siluf(float x) { return x / (1.f + __expf(-x)); }

#define MFMA16(a, b, c) __builtin_amdgcn_mfma_f32_16x16x32_bf16(a, b, c, 0, 0, 0)
#define WAITV(n) asm volatile("s_waitcnt vmcnt(" #n ")" ::: "memory")
#define SBAR() asm volatile("s_barrier" ::: "memory")

// ---------------------------------------------------------------- fp32 -> bf16
__global__ __launch_bounds__(256) void k_cvt(const float* __restrict__ in,
                                             bf16_t* __restrict__ out, int n4) {
  int i = blockIdx.x * 256 + threadIdx.x;
  if (i >= n4) return;
  const float4 f = ((const float4*)in)[i];
  bf16x4 r;
  r[0] = (bf16_t)f.x; r[1] = (bf16_t)f.y; r[2] = (bf16_t)f.z; r[3] = (bf16_t)f.w;
  ((bf16x4*)out)[i] = r;
}

// W_b rows 0..31, W_a rows 32..63, zeros 64..127
__global__ __launch_bounds__(256) void k_build_wba(const float* __restrict__ wb,
                                                   const float* __restrict__ wa,
                                                   bf16_t* __restrict__ out) {
  int i = blockIdx.x * 256 + threadIdx.x;
  int e = i * 4;
  int row = e >> 11;
  int col = e & 2047;
  float4 f = make_float4(0.f, 0.f, 0.f, 0.f);
  if (row < 32)      f = *(const float4*)&wb[row * 2048 + col];
  else if (row < 64) f = *(const float4*)&wa[(row - 32) * 2048 + col];
  bf16x4 r;
  r[0] = (bf16_t)f.x; r[1] = (bf16_t)f.y; r[2] = (bf16_t)f.z; r[3] = (bf16_t)f.w;
  *(bf16x4*)&out[e] = r;
}

// ---------------------------------------------------------------- GEMM (m97-style)
// Kept for the small N=128 (ba) GEMM.
template<bool OUT_BF16>
__global__ __launch_bounds__(256) void gemm_bt(const bf16_t* __restrict__ A,
                                               const bf16_t* __restrict__ B,
                                               void* __restrict__ Cout,
                                               int M, int N, int K) {
  __shared__ __align__(16) bf16_t As[4096];
  __shared__ __align__(16) bf16_t Bs[4096];
  const int tid  = threadIdx.x;
  const int lane = tid & 63;
  const int wave = tid >> 6;
  const int quad = lane >> 4;
  const int l16  = lane & 15;
  const int wr   = (wave >> 1) * 64;
  const int wc   = (wave & 1) * 64;
  const int m0   = blockIdx.y * 128;
  const int n0   = blockIdx.x * 128;
  const int ra   = tid >> 2;
  const int ca   = (tid & 3) * 8;

  const bf16_t* gA = A + (size_t)(m0 + ra) * K + ca;
  const bf16_t* gB = B + (size_t)(n0 + ra) * K + ca;
  bf16_t* lA = &As[tid * 8];
  bf16_t* lB = &Bs[tid * 8];

  floatx4 acc[4][4] = {};

  for (int k0 = 0; k0 < K; k0 += 32) {
    __syncthreads();
    async16(gA + k0, lA);
    async16(gA + k0 + (size_t)64 * K, lA + 2048);
    async16(gB + k0, lB);
    async16(gB + k0 + (size_t)64 * K, lB + 2048);
    __syncthreads();
    bf16x8 af[4], bfr[4];
#pragma unroll
    for (int i = 0; i < 4; ++i) {
      af[i]  = *(const bf16x8*)&As[(wr + i * 16 + l16) * 32 + quad * 8];
      bfr[i] = *(const bf16x8*)&Bs[(wc + i * 16 + l16) * 32 + quad * 8];
    }
#pragma unroll
    for (int mi = 0; mi < 4; ++mi)
#pragma unroll
      for (int ni = 0; ni < 4; ++ni)
        acc[mi][ni] = MFMA16(af[mi], bfr[ni], acc[mi][ni]);
  }

#pragma unroll
  for (int mi = 0; mi < 4; ++mi) {
#pragma unroll
    for (int ni = 0; ni < 4; ++ni) {
      const int row = m0 + wr + mi * 16 + quad * 4;
      const int col = n0 + wc + ni * 16 + l16;
#pragma unroll
      for (int r = 0; r < 4; ++r) {
        if (OUT_BF16)
          ((bf16_t*)Cout)[(size_t)(row + r) * N + col] = (bf16_t)acc[mi][ni][r];
        else
          ((float*)Cout)[(size_t)(row + r) * N + col] = acc[mi][ni][r];
      }
    }
  }
}

// ---------------------------------------------------------------- 8-phase 256x256 GEMM (BK=64)
// Full T-stack: T1 XCD swizzle, T2 LDS swizzle, T3 8-phase, T4 counted vmcnt,
// T5 setprio. 512 thr = 8 waves (2M x 4N), per-wave C = 128x64.
// LDS: 2 dbuf x (A[256][64] + B[256][64]) = 128 KB. K-tile X in buf X&1.
// Per K-tile, 4 phases = C-quadrants; 16 MFMA/phase, 1 half-tile staged/phase:
//   P1: stage A(X+1).lo   P2: stage A(X+1).hi
//   P3: stage B(X+2).lo   P4: stage B(X+2).hi ; vmcnt(4)
// Swizzle: LDS[row][c8] = G[row][c8 ^ (row&7)]; source pre-swizzled (rule #21).
// SPLIT-STORE epilogue: B spans wqkv||wz (N = 8192 + 4096 contiguous rows);
// tiles with n0 < NSPLIT write C0 (pitch NSPLIT), else C1 (pitch N - NSPLIT).
// 256-wide tiles never straddle the boundary (NSPLIT % 256 == 0).
__global__ __launch_bounds__(512, 1) void gemm8p(const bf16_t* __restrict__ A,
                                                 const bf16_t* __restrict__ B,
                                                 bf16_t* __restrict__ C0,
                                                 bf16_t* __restrict__ C1,
                                                 int M, int N, int K, int NSPLIT) {
  extern __shared__ __align__(16) bf16_t sm[];
  const int tid  = threadIdx.x;
  const int lane = tid & 63;
  const int wave = tid >> 6;   // 0..7
  const int quad = lane >> 4;
  const int l16  = lane & 15;
  const int wm   = wave >> 2;  // M half (128 rows)
  const int wn   = wave & 3;   // N quarter (64 cols)

  // T1: bijective XCD swizzle (caller guarantees nwg % 8 == 0)
  const int gx  = (int)gridDim.x;
  const int nwg = gx * (int)gridDim.y;
  const int id  = (int)blockIdx.y * gx + (int)blockIdx.x;
  const int cpx = nwg >> 3;
  const int sw  = (id & 7) * cpx + (id >> 3);
  const int m0  = (sw / gx) * 256;
  const int n0  = (sw % gx) * 256;

  // staging: one half-tile = [128][64] bf16 = 16KB = 512 thr x 2 x 16B.
  const int rowg   = tid >> 3;
  const int colsrc = (tid & 7) ^ (rowg & 7);
  const bf16_t* gAs = A + (size_t)(m0 + rowg) * K + colsrc * 8;
  const bf16_t* gBs = B + (size_t)(n0 + rowg) * K + colsrc * 8;
  bf16_t* lds0 = sm + tid * 8;

#define STG_A8(u, kt, ht) {                                     \
    bf16_t* la = lds0 + (u) * 32768 + (ht) * 8192;              \
    const bf16_t* ga = gAs + (size_t)(ht) * 128 * K + (kt) * 64;\
    async16(ga, la); async16(ga + (size_t)64 * K, la + 4096); }
#define STG_B8(u, kt, ht) {                                     \
    bf16_t* lb = lds0 + (u) * 32768 + 16384 + (ht) * 8192;      \
    const bf16_t* gb = gBs + (size_t)(ht) * 128 * K + (kt) * 64;\
    async16(gb, lb); async16(gb + (size_t)64 * K, lb + 4096); }

  // fragment read constants (row&7 == l16&7 for all frag rows)
  const int x7  = l16 & 7;
  const int cA0 = ((quad + 0) ^ x7) * 8;  // kk=0 swizzled 8-elem slot
  const int cA1 = ((quad + 4) ^ x7) * 8;  // kk=1
  const int eA0 = (wm * 128 + l16) * 64;
  const int eB0 = 16384 + (wn * 64 + l16) * 64;

  floatx4 acc[8][4] = {};
  const int KT = K >> 6;  // BK=64; caller guarantees K%64==0, KT>=3

  // ---- prologue: A0.lo A0.hi B0.lo B0.hi B1.lo B1.hi (12 loads)
  STG_A8(0, 0, 0); STG_A8(0, 0, 1);
  STG_B8(0, 0, 0); STG_B8(0, 0, 1);
  STG_B8(1, 1, 0); STG_B8(1, 1, 1);
  WAITV(4);
  SBAR();

  bf16x8 af[4][2], bn0[2][2], bn1[2][2];
  for (int X = 0; X < KT; ++X) {
    const int c = X & 1;
    const bf16_t* sb = sm + c * 32768;

    // ---- P1: (mh0, nh0); read A-mh0 (8) + B-nh0 (4); stage A(X+1).lo
#pragma unroll
    for (int i = 0; i < 4; ++i) {
      af[i][0] = *(const bf16x8*)&sb[eA0 + i * 1024 + cA0];
      af[i][1] = *(const bf16x8*)&sb[eA0 + i * 1024 + cA1];
    }
#pragma unroll
    for (int j = 0; j < 2; ++j) {
      bn0[j][0] = *(const bf16x8*)&sb[eB0 + j * 1024 + cA0];
      bn0[j][1] = *(const bf16x8*)&sb[eB0 + j * 1024 + cA1];
    }
    if (X + 1 < KT) STG_A8(c ^ 1, X + 1, 0);
    SBAR();
    __builtin_amdgcn_s_setprio(1);
#pragma unroll
    for (int i = 0; i < 4; ++i)
#pragma unroll
      for (int j = 0; j < 2; ++j) {
        acc[i][j] = MFMA16(af[i][0], bn0[j][0], acc[i][j]);
        acc[i][j] = MFMA16(af[i][1], bn0[j][1], acc[i][j]);
      }
    __builtin_amdgcn_s_setprio(0);
    SBAR();

    // ---- P2: (mh0, nh1); read B-nh1 (4); stage A(X+1).hi
#pragma unroll
    for (int j = 0; j < 2; ++j) {
      bn1[j][0] = *(const bf16x8*)&sb[eB0 + (2 + j) * 1024 + cA0];
      bn1[j][1] = *(const bf16x8*)&sb[eB0 + (2 + j) * 1024 + cA1];
    }
    if (X + 1 < KT) STG_A8(c ^ 1, X + 1, 1);
    SBAR();
    __builtin_amdgcn_s_setprio(1);
#pragma unroll
    for (int i = 0; i < 4; ++i)
#pragma unroll
      for (int j = 0; j < 2; ++j) {
        acc[i][2 + j] = MFMA16(af[i][0], bn1[j][0], acc[i][2 + j]);
        acc[i][2 + j] = MFMA16(af[i][1], bn1[j][1], acc[i][2 + j]);
      }
    __builtin_amdgcn_s_setprio(0);
    SBAR();

    // ---- P3: (mh1, nh0); read A-mh1 (8); stage B(X+2).lo
#pragma unroll
    for (int i = 0; i < 4; ++i) {
      af[i][0] = *(const bf16x8*)&sb[eA0 + (4 + i) * 1024 + cA0];
      af[i][1] = *(const bf16x8*)&sb[eA0 + (4 + i) * 1024 + cA1];
    }
    if (X + 2 < KT) STG_B8(c, X + 2, 0);
    SBAR();
    __builtin_amdgcn_s_setprio(1);
#pragma unroll
    for (int i = 0; i < 4; ++i)
#pragma unroll
      for (int j = 0; j < 2; ++j) {
        acc[4 + i][j] = MFMA16(af[i][0], bn0[j][0], acc[4 + i][j]);
        acc[4 + i][j] = MFMA16(af[i][1], bn0[j][1], acc[4 + i][j]);
      }
    __builtin_amdgcn_s_setprio(0);
    SBAR();

    // ---- P4: (mh1, nh1); stage B(X+2).hi; counted vmcnt
    if (X + 2 < KT) { STG_B8(c, X + 2, 1); WAITV(4); }
    else            { WAITV(0); }
    SBAR();
    __builtin_amdgcn_s_setprio(1);
#pragma unroll
    for (int i = 0; i < 4; ++i)
#pragma unroll
      for (int j = 0; j < 2; ++j) {
        acc[4 + i][2 + j] = MFMA16(af[i][0], bn1[j][0], acc[4 + i][2 + j]);
        acc[4 + i][2 + j] = MFMA16(af[i][1], bn1[j][1], acc[4 + i][2 + j]);
      }
    __builtin_amdgcn_s_setprio(0);
    SBAR();
  }
#undef STG_A8
#undef STG_B8

  // ---- split-store epilogue (proven C/D mapping)
  const bool lo = (n0 < NSPLIT);
  bf16_t* Cb = lo ? C0 : C1;
  const int pitch = lo ? NSPLIT : (N - NSPLIT);
  const int ncol0 = lo ? n0 : (n0 - NSPLIT);
#pragma unroll
  for (int mi = 0; mi < 8; ++mi) {
#pragma unroll
    for (int ni = 0; ni < 4; ++ni) {
      const int row = m0 + wm * 128 + mi * 16 + quad * 4;
      const int col = ncol0 + wn * 64 + ni * 16 + l16;
#pragma unroll
      for (int r = 0; r < 4; ++r)
        Cb[(size_t)(row + r) * pitch + col] = (bf16_t)acc[mi][ni][r];
    }
  }
}

// ---------------------------------------------------------------- big-tile deep-pipelined GEMM
// MH=1: BM=128 (N=2048 out-GEMM: grid (8,32)=256 blocks -> full GPU),
// 2-phase, per-wave loads/K-tile = 3 -> vmcnt 6/3/0; ring 4 x 24KB = 96KB LDS.
template<int MH, bool OUT_BF16>
__global__ __launch_bounds__(512, 1) void gemm_big(const bf16_t* __restrict__ A,
                                                   const bf16_t* __restrict__ B,
                                                   void* __restrict__ Cout,
                                                   int M, int N, int K) {
  extern __shared__ __align__(16) bf16_t sm[];
  constexpr int BM    = MH * 128;
  constexpr int MFRAG = MH * 4;
  constexpr int HF    = MFRAG / 2;
  constexpr int BUFE  = MH * 4096 + 8192;  // elems per ring buffer (A + B)
  const int tid  = threadIdx.x;
  const int lane = tid & 63;
  const int wave = tid >> 6;   // 0..7
  const int quad = lane >> 4;
  const int l16  = lane & 15;
  const int wm   = wave >> 2;  // 0..1  M half
  const int wn   = wave & 3;   // 0..3  N quarter (64 cols)

  // bijective XCD swizzle (caller guarantees nwg % 8 == 0)
  const int gx  = (int)gridDim.x;
  const int nwg = gx * (int)gridDim.y;
  const int id  = (int)blockIdx.y * gx + (int)blockIdx.x;
  const int cpx = nwg >> 3;
  const int sw  = (id & 7) * cpx + (id >> 3);
  const int m0  = (sw / gx) * BM;
  const int n0  = (sw % gx) * 256;

  // ---- staging addresses (each issue: 64 lanes x 16B = 16 rows x 64B)
  const int lr    = lane >> 2;                       // row within issue
  const int lslot = (lane & 3) ^ ((lane >> 3) & 3);  // pre-swizzled 16B slot
  const bf16_t* gA = A + (size_t)(m0 + wave * (MH * 16) + lr) * K + lslot * 8;
  const bf16_t* gB = B + (size_t)(n0 + wave * 32 + lr) * K + lslot * 8;
  const int ldsA0 = wave * (MH * 512) + lane * 8;
  const int ldsB0 = MH * 4096 + wave * 1024 + lane * 8;

#define STG_A(u, kt) {                                          \
    bf16_t* la = sm + (u) * BUFE + ldsA0;                       \
    const bf16_t* ga = gA + (size_t)(kt) * 32;                  \
    async16(ga, la);                                            \
    if constexpr (MH == 2) async16(ga + (size_t)16 * K, la + 512); }
#define STG_B(u, kt) {                                          \
    bf16_t* lb = sm + (u) * BUFE + ldsB0;                       \
    const bf16_t* gb = gB + (size_t)(kt) * 32;                  \
    async16(gb, lb);                                            \
    async16(gb + (size_t)16 * K, lb + 512); }

  int offA[MFRAG], offB[4];
#pragma unroll
  for (int i = 0; i < MFRAG; ++i) {
    int ra = wm * (MFRAG * 16) + i * 16 + l16;
    offA[i] = (ra * 32 + quad * 8) ^ (((ra >> 1) & 3) << 3);
  }
#pragma unroll
  for (int i = 0; i < 4; ++i) {
    int rb = wn * 64 + i * 16 + l16;
    offB[i] = MH * 4096 + ((rb * 32 + quad * 8) ^ (((rb >> 1) & 3) << 3));
  }

  floatx4 acc[MFRAG][4] = {};
  const int KT = K >> 5;  // caller guarantees KT >= 4

  STG_A(0, 0); STG_B(0, 0);
  STG_A(1, 1); STG_B(1, 1);
  STG_A(2, 2); STG_B(2, 2);
  if constexpr (MH == 2) WAITV(8); else WAITV(6);
  SBAR();

  for (int U = 0; U < KT; ++U) {
    const int bu = U & 3;
    const bf16_t* sb = sm + bu * BUFE;
    const int un = U + 3;
    const int tu = un & 3;
    bf16x8 af[HF], bfr[4];

    // ---- phase 0: M lower half; stage A(U+3)
#pragma unroll
    for (int i = 0; i < HF; ++i) af[i] = *(const bf16x8*)&sb[offA[i]];
#pragma unroll
    for (int i = 0; i < 4; ++i) bfr[i] = *(const bf16x8*)&sb[offB[i]];
    if (un < KT) STG_A(tu, un);
    SBAR();
    __builtin_amdgcn_s_setprio(1);
#pragma unroll
    for (int mi = 0; mi < HF; ++mi)
#pragma unroll
      for (int ni = 0; ni < 4; ++ni)
        acc[mi][ni] = MFMA16(af[mi], bfr[ni], acc[mi][ni]);
    __builtin_amdgcn_s_setprio(0);
    SBAR();

    // ---- phase 1: M upper half; stage B(U+3); counted vmcnt
#pragma unroll
    for (int i = 0; i < HF; ++i) af[i] = *(const bf16x8*)&sb[offA[HF + i]];
    if (un < KT) STG_B(tu, un);
    if (un < KT)         { if constexpr (MH == 2) WAITV(8); else WAITV(6); }
    else if (U + 2 < KT) { if constexpr (MH == 2) WAITV(4); else WAITV(3); }
    else                 WAITV(0);
    SBAR();
    __builtin_amdgcn_s_setprio(1);
#pragma unroll
    for (int mi = 0; mi < HF; ++mi)
#pragma unroll
      for (int ni = 0; ni < 4; ++ni)
        acc[HF + mi][ni] = MFMA16(af[mi], bfr[ni], acc[HF + mi][ni]);
    __builtin_amdgcn_s_setprio(0);
    SBAR();
  }
#undef STG_A
#undef STG_B

#pragma unroll
  for (int mi = 0; mi < MFRAG; ++mi) {
#pragma unroll
    for (int ni = 0; ni < 4; ++ni) {
      const int row = m0 + wm * (MFRAG * 16) + mi * 16 + quad * 4;
      const int col = n0 + wn * 64 + ni * 16 + l16;
#pragma unroll
      for (int r = 0; r < 4; ++r) {
        if (OUT_BF16)
          ((bf16_t*)Cout)[(size_t)(row + r) * N + col] = (bf16_t)acc[mi][ni][r];
        else
          ((float*)Cout)[(size_t)(row + r) * N + col] = acc[mi][ni][r];
      }
    }
  }
}

// ---------------------------------------------------------------- beta / g ([h][t] layout)
__global__ __launch_bounds__(256) void k_betag(const float* __restrict__ cba,
                                               const float* __restrict__ A_log,
                                               const float* __restrict__ dtb,
                                               float* __restrict__ beta_t,
                                               float* __restrict__ g_t) {
  int i = blockIdx.x * 256 + threadIdx.x;  // T*32
  int t = i >> 5, h = i & 31;
  float b = cba[t * 128 + h];
  float a = cba[t * 128 + 32 + h];
  beta_t[h * 4096 + t] = 1.f / (1.f + __expf(-b));
  float x = a + dtb[h];
  float sp = (x > 20.f) ? x : log1pf(__expf(x));
  g_t[h * 4096 + t] = -__expf(A_log[h]) * sp;
}

// ---------------------------------------------------------------- conv4 + silu + l2norm
__global__ __launch_bounds__(64) void k_conv(const bf16_t* __restrict__ mixed,
                                             const float* __restrict__ cw,
                                             bf16_t* __restrict__ qo,
                                             bf16_t* __restrict__ ko,
                                             bf16_t* __restrict__ vo) {
  const int grp = blockIdx.x;
  const int t0 = blockIdx.y * 8;
  const int l = threadIdx.x;
  const int c0 = grp * 128 + l;
  const int c1 = c0 + 64;
  const float4 w0 = *(const float4*)&cw[c0 * 4];
  const float4 w1 = *(const float4*)&cw[c1 * 4];
  float h0[3], h1[3];
#pragma unroll
  for (int j = 0; j < 3; ++j) {
    int tt = t0 - 3 + j;
    h0[j] = (tt >= 0) ? (float)mixed[(size_t)tt * 8192 + c0] : 0.f;
    h1[j] = (tt >= 0) ? (float)mixed[(size_t)tt * 8192 + c1] : 0.f;
  }
#pragma unroll
  for (int i = 0; i < 8; ++i) {
    const int t = t0 + i;
    float x0 = (float)mixed[(size_t)t * 8192 + c0];
    float x1 = (float)mixed[(size_t)t * 8192 + c1];
    float a0 = w0.x * h0[0] + w0.y * h0[1] + w0.z * h0[2] + w0.w * x0;
    float a1 = w1.x * h1[0] + w1.y * h1[1] + w1.z * h1[2] + w1.w * x1;
    h0[0] = h0[1]; h0[1] = h0[2]; h0[2] = x0;
    h1[0] = h1[1]; h1[1] = h1[2]; h1[2] = x1;
    float v0 = siluf(a0), v1 = siluf(a1);
    if (grp < 32) {
      float s = v0 * v0 + v1 * v1;
#pragma unroll
      for (int m = 1; m < 64; m <<= 1) s += __shfl_xor(s, m);
      float r = rsqrtf(s + 1e-6f);
      if (grp < 16) {
        bf16_t* q = qo + ((size_t)t * 16 + grp) * 128;
        q[l]      = (bf16_t)(v0 * r * 0.08838834764831845f);  // DK^-0.5 folded
        q[l + 64] = (bf16_t)(v1 * r * 0.08838834764831845f);
      } else {
        bf16_t* k = ko + ((size_t)t * 16 + grp - 16) * 128;
        k[l]      = (bf16_t)(v0 * r);
        k[l + 64] = (bf16_t)(v1 * r);
      }
    } else {
      bf16_t* v = vo + ((size_t)t * 32 + grp - 32) * 128;
      v[l]      = (bf16_t)v0;
      v[l + 64] = (bf16_t)v1;
    }
  }
}

// ---------------------------------------------------------------- k_prep
__global__ __launch_bounds__(256, 2) void k_prep(
    const bf16_t* __restrict__ qg, const bf16_t* __restrict__ kg,
    const bf16_t* __restrict__ vg,
    const float* __restrict__ bb_t, const float* __restrict__ gb_t,
    bf16_t* __restrict__ Vt, bf16_t* __restrict__ Wlo, bf16_t* __restrict__ Whi,
    bf16_t* __restrict__ Mout, bf16_t* __restrict__ kt, float* __restrict__ smalls) {
  const int c = blockIdx.x >> 5;
  const int h = blockIdx.x & 31;
  const int kh = h >> 1;
  const int t0 = c * 64;
  const int tid = threadIdx.x, lane = tid & 63, wave = tid >> 6;
  const int quad = lane >> 4, l16 = lane & 15;

  __shared__ __align__(16) bf16_t lsKQ[2][64][136];
  __shared__ float lsC[64][68];
  __shared__ float lsG[64], lsA[64], lsSc[64], lsBeta[64];

  {
    const int r = tid >> 2, s0 = (tid & 3) * 32;
    const bf16_t* kr = kg + ((size_t)(t0 + r) * 16 + kh) * 128 + s0;
    const bf16_t* qr = qg + ((size_t)(t0 + r) * 16 + kh) * 128 + s0;
#pragma unroll
    for (int j = 0; j < 4; ++j) {
      *(uint4*)&lsKQ[0][r][s0 + j * 8] = *(const uint4*)&kr[j * 8];
      *(uint4*)&lsKQ[1][r][s0 + j * 8] = *(const uint4*)&qr[j * 8];
    }
  }
  if (wave == 0) {
    float gv = gb_t[(size_t)h * 4096 + t0 + lane];
#pragma unroll
    for (int off = 1; off < 64; off <<= 1) {
      float n = __shfl_up(gv, off);
      if (lane >= off) gv += n;
    }
    float GL = __shfl(gv, 63);
    lsG[lane] = gv;
    lsA[lane] = __expf(gv);
    lsSc[lane] = __expf(GL - gv);
    lsBeta[lane] = bb_t[(size_t)h * 4096 + t0 + lane];
  }
  __syncthreads();

  const int mr = (wave >> 1) * 32, nr = (wave & 1) * 32;
  floatx4 ak[2][2] = {}, aq[2][2] = {};
  if (wave != 1) {
#pragma unroll
    for (int ks = 0; ks < 4; ++ks) {
      bf16x8 yf[2], xk[2], xq[2];
#pragma unroll
      for (int i = 0; i < 2; ++i) {
        yf[i] = *(const bf16x8*)&lsKQ[0][nr + i * 16 + l16][ks * 32 + quad * 8];
        xk[i] = *(const bf16x8*)&lsKQ[0][mr + i * 16 + l16][ks * 32 + quad * 8];
        xq[i] = *(const bf16x8*)&lsKQ[1][mr + i * 16 + l16][ks * 32 + quad * 8];
      }
#pragma unroll
      for (int i = 0; i < 2; ++i)
#pragma unroll
        for (int j = 0; j < 2; ++j) {
          ak[i][j] = MFMA16(xk[i], yf[j], ak[i][j]);
          aq[i][j] = MFMA16(xq[i], yf[j], aq[i][j]);
        }
    }
  }
  bf16_t* Mb = Mout + (size_t)(h * 64 + c) * 4096;
#pragma unroll
  for (int i = 0; i < 2; ++i)
#pragma unroll
    for (int j = 0; j < 2; ++j)
#pragma unroll
      for (int r = 0; r < 4; ++r) {
        int t = mr + i * 16 + quad * 4 + r;
        int s = nr + j * 16 + l16;
        float e = __expf(lsG[t] - lsG[s]);
        float cv = (s < t) ? lsBeta[t] * e * ak[i][j][r] : 0.f;
        float mv = (s <= t) ? e * aq[i][j][r] : 0.f;
        if (wave != 1) lsC[t][s] = cv;
        Mb[t * 64 + s] = (bf16_t)mv;
      }
  __syncthreads();

  // forward substitution: thread <-> column. cols 0..127: V, 128..255: W-rhs
  const int col = tid & 127;
  const bool isW = tid >= 128;
  float vals[64];
#pragma unroll
  for (int t = 0; t < 64; ++t) {
    float b;
    if (!isW) b = (float)vg[((size_t)(t0 + t) * 32 + h) * 128 + col];
    else      b = lsA[t] * (float)lsKQ[0][t][col];
    vals[t] = lsBeta[t] * b;
  }
#pragma unroll
  for (int t = 1; t < 64; ++t) {
    float acc = vals[t];
#pragma unroll
    for (int s4 = 0; s4 <= (t - 1) >> 2; ++s4) {
      float4 cv = *(const float4*)&lsC[t][s4 * 4];
      acc -= cv.x * vals[s4 * 4 + 0];
      acc -= cv.y * vals[s4 * 4 + 1];
      acc -= cv.z * vals[s4 * 4 + 2];
      acc -= cv.w * vals[s4 * 4 + 3];
    }
    vals[t] = acc;
  }

  // V columns: direct transposed write (VtT[dv][t], contiguous in t)
  if (!isW) {
    bf16_t* vd = Vt + (size_t)(h * 64 + c) * 8192 + (size_t)col * 64;
#pragma unroll
    for (int j = 0; j < 16; ++j) {
      bf16x4 p;
      p[0] = (bf16_t)vals[j * 4 + 0];
      p[1] = (bf16_t)vals[j * 4 + 1];
      p[2] = (bf16_t)vals[j * 4 + 2];
      p[3] = (bf16_t)vals[j * 4 + 3];
      *(bf16x4*)&vd[j * 4] = p;
    }
  } else {
#pragma unroll
    for (int t = 0; t < 64; ++t) vals[t] = -vals[t];  // W' = -W
  }

  // K^T for the chain
  if ((h & 1) == 0) {
    const int dk = tid >> 1, sh = (tid & 1) * 32;
    bf16_t* kd = kt + (size_t)(c * 16 + kh) * 8192 + (size_t)dk * 64 + sh;
#pragma unroll
    for (int j4 = 0; j4 < 4; ++j4) {
      bf16x8 v;
#pragma unroll
      for (int e = 0; e < 8; ++e) v[e] = lsKQ[0][sh + j4 * 8 + e][dk];
      *(bf16x8*)&kd[j4 * 8] = v;
    }
  }
  if (tid < 64) {
    float* sm = smalls + (size_t)(h * 64 + c) * 128;
    sm[tid] = lsA[tid];
    sm[64 + tid] = lsSc[tid];
  }
  __syncthreads();

  // transpose W half via LDS (overlay lsKQ), pitch 272
  bf16_t* lsT = &lsKQ[0][0][0];
  if (isW) {
#pragma unroll
    for (int t = 0; t < 64; ++t) lsT[t * 272 + tid] = (bf16_t)vals[t];
  }
  __syncthreads();

  // cooperative vectorized W' write: [t][dk 128]
  {
    const int r = tid >> 2, part = tid & 3;
    const bf16_t* src = &lsT[r * 272 + 128 + part * 32];
    bf16_t* Wb = (h < 16 ? Wlo : Whi) + (size_t)((h & 15) * 64 + c) * 8192 + r * 128 + part * 32;
#pragma unroll
    for (int j = 0; j < 4; ++j)
      *(uint4*)&Wb[j * 8] = *(const uint4*)&src[j * 8];
  }
}

// ---------------------------------------------------------------- k_chain (4-wave, dv-eighth)
// grid = 256: blockIdx = q*32 + h, q = dv-eighth (16 cols). q*32 ≡ 0 mod 8,
// so a head's 8 eighth-blocks land on the SAME XCD -> shared L2 for the
// W/Q/K/M streams all eight read. ALL 256 CUs active. 256 threads = 4 waves
// (1/SIMD; lockstep multi-wave REGRESSED R2; paired-group shared-barrier
// variant REGRESSED R7 — barrier forces groups into phase, no offset).
// Per chunk: X = Vt + W'.S ; o = A*(Q.S) + M.X ; S' = aL*S + K^T.(sc*X)
// S^T slice [dv 16][dk 128] lives in lsS[16][136].
__global__ __launch_bounds__(256, 1) void k_chain(
    const bf16_t* __restrict__ qg, const bf16_t* __restrict__ VtT,
    const bf16_t* __restrict__ Wlo, const bf16_t* __restrict__ Whi,
    const bf16_t* __restrict__ Mg, const bf16_t* __restrict__ ktg,
    const float* __restrict__ smalls, bf16_t* __restrict__ o) {
  const int h = blockIdx.x & 31;
  const int dv0 = (blockIdx.x >> 5) * 16;
  const int kh = h >> 1;
  const int tid = threadIdx.x, lane = tid & 63, wave = tid >> 6;
  const int quad = lane >> 4, l16 = lane & 15;
  const int trow = wave * 16 + quad * 4;

  __shared__ __align__(16) bf16_t lsXT[16][72];
  __shared__ __align__(16) bf16_t lsXbT[16][72];
  __shared__ __align__(16) bf16_t lsS[16][136];

  const bf16_t* Wbase = (h < 16 ? Wlo : Whi) + (size_t)(h & 15) * 64 * 8192;
  const bf16_t* Vbase = VtT + (size_t)h * 64 * 8192;
  const bf16_t* Mbase = Mg + (size_t)h * 64 * 4096;
  const float*  Sbase = smalls + (size_t)h * 64 * 128;

  // running per-wave pointers (advanced by constant strides per chunk)
  const bf16_t* pW = Wbase + (size_t)(wave * 16 + l16) * 128 + quad * 8;
  const bf16_t* pQ = qg + ((size_t)(wave * 16 + l16) * 16 + kh) * 128 + quad * 8;
  const bf16_t* pK = ktg + (size_t)kh * 8192 + (size_t)(wave * 16 + l16) * 64 + quad * 8;
  const bf16_t* pM = Mbase + (size_t)(wave * 16 + l16) * 64 + quad * 8;
  const bf16_t* pV = Vbase + (size_t)(dv0 + l16) * 64 + trow;
  const float*  pS = Sbase;

  floatx4 sacc[2] = {};
  for (int i = tid; i < 16 * 136; i += 256) (&lsS[0][0])[i] = (bf16_t)0.f;

  bf16x8 nW[4], nQ[4], nK[4], nM[2];
  bf16x4 nV;
  float4 nA, nSc;
  float nAL;
  {
#pragma unroll
    for (int ks = 0; ks < 4; ++ks) {
      nW[ks] = *(const bf16x8*)&pW[ks * 32];
      nQ[ks] = *(const bf16x8*)&pQ[ks * 32];
    }
    nK[0] = *(const bf16x8*)&pK[0];
    nK[1] = *(const bf16x8*)&pK[32];
    nK[2] = *(const bf16x8*)&pK[4096];
    nK[3] = *(const bf16x8*)&pK[4096 + 32];
    nM[0] = *(const bf16x8*)&pM[0];
    nM[1] = *(const bf16x8*)&pM[32];
    nV = *(const bf16x4*)&pV[0];
    nA  = *(const float4*)&pS[trow];
    nSc = *(const float4*)&pS[64 + trow];
    nAL = pS[63];
    pW += 8192; pQ += 131072; pK += 131072; pM += 4096; pV += 8192; pS += 128;
  }
  __syncthreads();

  for (int cc = 0; cc < 64; ++cc) {
    const int t0 = cc * 64;
    bf16x8 cW[4], cQ[4], cK[4], cM[2];
    float cV[4];
    float4 cA = nA, cSc = nSc;
    float cAL = nAL;
#pragma unroll
    for (int ks = 0; ks < 4; ++ks) { cW[ks] = nW[ks]; cQ[ks] = nQ[ks]; cK[ks] = nK[ks]; }
    cM[0] = nM[0]; cM[1] = nM[1];
#pragma unroll
    for (int r = 0; r < 4; ++r) cV[r] = (float)nV[r];

    if (cc + 1 < 64) {
#pragma unroll
      for (int ks = 0; ks < 4; ++ks) {
        nW[ks] = *(const bf16x8*)&pW[ks * 32];
        nQ[ks] = *(const bf16x8*)&pQ[ks * 32];
      }
      nK[0] = *(const bf16x8*)&pK[0];
      nK[1] = *(const bf16x8*)&pK[32];
      nK[2] = *(const bf16x8*)&pK[4096];
      nK[3] = *(const bf16x8*)&pK[4096 + 32];
      nM[0] = *(const bf16x8*)&pM[0];
      nM[1] = *(const bf16x8*)&pM[32];
      nV = *(const bf16x4*)&pV[0];
      nA  = *(const float4*)&pS[trow];
      nSc = *(const float4*)&pS[64 + trow];
      nAL = pS[63];
      pW += 8192; pQ += 131072; pK += 131072; pM += 4096; pV += 8192; pS += 128;
    }

    // ---- P0: X = Vt + W'.S  (bS kept in regs)
    bf16x8 bS[4];
#pragma unroll
    for (int ks = 0; ks < 4; ++ks)
      bS[ks] = *(const bf16x8*)&lsS[l16][ks * 32 + quad * 8];
    floatx4 xacc;
#pragma unroll
    for (int r = 0; r < 4; ++r) xacc[r] = cV[r];
#pragma unroll
    for (int ks = 0; ks < 4; ++ks)
      xacc = MFMA16(cW[ks], bS[ks], xacc);
    {
      bf16x4 px, pb;
#pragma unroll
      for (int r = 0; r < 4; ++r) {
        px[r] = (bf16_t)xacc[r];
        pb[r] = (bf16_t)(xacc[r] * ((const float*)&cSc)[r]);
      }
      *(bf16x4*)&lsXT[l16][trow] = px;
      *(bf16x4*)&lsXbT[l16][trow] = pb;
    }
    // ---- independent reg-only work (hides the ds_write drain before B1):
    floatx4 qacc = {};
#pragma unroll
    for (int ks = 0; ks < 4; ++ks)
      qacc = MFMA16(cQ[ks], bS[ks], qacc);
#pragma unroll
    for (int r = 0; r < 4; ++r) qacc[r] *= ((const float*)&cA)[r];
#pragma unroll
    for (int mh = 0; mh < 2; ++mh)
#pragma unroll
      for (int r = 0; r < 4; ++r) sacc[mh][r] *= cAL;
    barrier_lds();  // B1: X ready; all lsS reads done

    // ---- P1 (short): o += M.X ; store o
#pragma unroll
    for (int ks = 0; ks < 2; ++ks) {
      bf16x8 bX = *(const bf16x8*)&lsXT[l16][ks * 32 + quad * 8];
      qacc = MFMA16(cM[ks], bX, qacc);
    }
#pragma unroll
    for (int r = 0; r < 4; ++r)
      o[((size_t)(t0 + trow + r) * 32 + h) * 128 + dv0 + l16] = (bf16_t)qacc[r];

    // ---- S' = aL*S + K^T.(sc*X)
#pragma unroll
    for (int ks = 0; ks < 2; ++ks) {
      bf16x8 bXb = *(const bf16x8*)&lsXbT[l16][ks * 32 + quad * 8];
#pragma unroll
      for (int mh = 0; mh < 2; ++mh)
        sacc[mh] = MFMA16(cK[mh * 2 + ks], bXb, sacc[mh]);
    }
    // ---- P2: refresh bf16 state (safe: all lsS reads happened before B1)
#pragma unroll
    for (int mh = 0; mh < 2; ++mh) {
      bf16x4 ps;
#pragma unroll
      for (int r = 0; r < 4; ++r) ps[r] = (bf16_t)sacc[mh][r];
      *(bf16x4*)&lsS[l16][(wave + 4 * mh) * 16 + quad * 4] = ps;
    }
    barrier_lds();  // B2: S visible; lsXT/lsXbT reads done before next P0 write
  }
}

// ---------------------------------------------------------------- RMSNorm * silu(z)
__global__ __launch_bounds__(256) void k_gate(const bf16_t* __restrict__ o,
                                              const bf16_t* __restrict__ z,
                                              const float* __restrict__ nw,
                                              bf16_t* __restrict__ y) {
  const int row = blockIdx.x * 4 + (threadIdx.x >> 6);  // t*32+h
  const int l = threadIdx.x & 63;
  const bf16_t* orow = o + (size_t)row * 128;
  float o0 = (float)orow[l], o1 = (float)orow[l + 64];
  float s = o0 * o0 + o1 * o1;
#pragma unroll
  for (int m = 1; m < 64; m <<= 1) s += __shfl_xor(s, m);
  float r = rsqrtf(s * (1.f / 128.f) + 1e-6f);
  const bf16_t* zrow = z + (size_t)row * 128;
  float z0 = (float)zrow[l], z1 = (float)zrow[l + 64];
  bf16_t* yrow = y + (size_t)row * 128;
  yrow[l]      = (bf16_t)(o0 * r * nw[l] * siluf(z0));
  yrow[l + 64] = (bf16_t)(o1 * r * nw[l + 64] * siluf(z1));
}

// ---------------------------------------------------------------- launch
extern "C" void kernel_launch(void* const* d_in, const int* in_sizes, int n_in,
                              void* d_out, int out_size, void* d_ws, size_t ws_size,
                              hipStream_t stream) {
  const float* hidden = (const float*)d_in[0];
  const float* W_qkv  = (const float*)d_in[1];
  const float* W_z    = (const float*)d_in[2];
  const float* W_b    = (const float*)d_in[3];
  const float* W_a    = (const float*)d_in[4];
  const float* conv_w = (const float*)d_in[5];
  const float* dt_b   = (const float*)d_in[6];
  const float* A_log  = (const float*)d_in[7];
  const float* norm_w = (const float*)d_in[8];
  const float* W_out  = (const float*)d_in[9];
  float* out = (float*)d_out;

  static int gemm_attr_done = 0;
  if (!gemm_attr_done) {
    hipFuncSetAttribute(reinterpret_cast<const void*>(&gemm8p),
                        hipFuncAttributeMaxDynamicSharedMemorySize, 131072);
    hipFuncSetAttribute(reinterpret_cast<const void*>(&gemm_big<1, false>),
                        hipFuncAttributeMaxDynamicSharedMemorySize, 98304);
    gemm_attr_done = 1;
  }

  char* w = (char*)d_ws;
  const size_t MB = 1024 * 1024;
  bf16_t* hs    = (bf16_t*)(w + 0 * MB);     // 16MB; after ba-GEMM -> W_lo
  bf16_t* Wlo   = hs;
  bf16_t* wqkv  = (bf16_t*)(w + 16 * MB);    // 32MB; -> VtT (prep) -> ybuf (gate)
  bf16_t* Vtb   = wqkv;
  bf16_t* ybuf  = wqkv;
  bf16_t* wz    = (bf16_t*)(w + 48 * MB);    // 16MB; ADJACENT to wqkv -> one
                                             //   contiguous B [12288][2048];
                                             //   later -> W_hi
  bf16_t* Whi   = wz;
  bf16_t* wout  = (bf16_t*)(w + 64 * MB);    // 16MB (live till end)
  bf16_t* wba   = (bf16_t*)(w + 80 * MB);    // 0.5MB
  bf16_t* mixed = (bf16_t*)(w + 81 * MB);    // 64MB (qkv out); after conv:
  bf16_t* obuf  = mixed;                     //   [obuf bf16 32MB @81]
  bf16_t* Mbuf  = (bf16_t*)(w + 113 * MB);   //   [M 16MB @113]
  bf16_t* ktb   = (bf16_t*)(w + 129 * MB);   //   [K^T 16MB @129]
  bf16_t* zbuf  = (bf16_t*)(w + 145 * MB);   // 32MB
  float*  cba   = (float*)(w + 177 * MB);    // 2MB; after betag -> smalls (1MB)
  float*  smalls= cba;
  bf16_t* qb    = (bf16_t*)(w + 179 * MB);   // 16MB
  bf16_t* kb    = (bf16_t*)(w + 195 * MB);   // 16MB
  bf16_t* vb    = (bf16_t*)(w + 211 * MB);   // 32MB
  float*  betab = (float*)(w + 243 * MB);    // 0.5MB [h][t]
  float*  gbuf  = (float*)(w + 243 * MB + 512 * 1024);  // 0.5MB [h][t]

  k_cvt<<<8192, 256, 0, stream>>>(hidden, hs, 2097152);
  k_cvt<<<16384, 256, 0, stream>>>(W_qkv, wqkv, 4194304);
  k_cvt<<<8192, 256, 0, stream>>>(W_z, wz, 2097152);
  k_cvt<<<8192, 256, 0, stream>>>(W_out, wout, 2097152);
  k_build_wba<<<256, 256, 0, stream>>>(W_b, W_a, wba);

  // ONE combined GEMM: B = [wqkv ; wz] (adjacent, 12288 rows), split-store
  // epilogue routes tiles to mixed (cols < 8192) or zbuf. grid %8==0.
  gemm8p<<<dim3(48, 16), 512, 131072, stream>>>(hs, wqkv, mixed, zbuf,
                                                4096, 12288, 2048, 8192);
  gemm_bt<false><<<dim3(1, 32), 256, 0, stream>>>(hs, wba, cba, 4096, 128, 2048);
  k_betag<<<512, 256, 0, stream>>>(cba, A_log, dt_b, betab, gbuf);

  k_conv<<<dim3(64, 512), 64, 0, stream>>>(mixed, conv_w, qb, kb, vb);

  k_prep<<<2048, 256, 0, stream>>>(qb, kb, vb, betab, gbuf,
                                   Vtb, Wlo, Whi, Mbuf, ktb, smalls);
  k_chain<<<256, 256, 0, stream>>>(qb, Vtb, Wlo, Whi, Mbuf, ktb, smalls, obuf);

  k_gate<<<32768, 256, 0, stream>>>(obuf, zbuf, norm_w, ybuf);
  // out-GEMM: 128x256 tile -> grid (8,32)=256 blocks (%8==0), full GPU. K=4096.
  gemm_big<1, false><<<dim3(8, 32), 512, 98304, stream>>>(ybuf, wout, out, 4096, 2048, 4096);
}

// Round 9
// 810.757 us; speedup vs baseline: 1.1373x; 1.0075x over previous
//
#include <hip/hip_runtime.h>
#include <cstdint>
#include <cstddef>

typedef __bf16 bf16_t;
typedef __bf16 bf16x8 __attribute__((ext_vector_type(8)));
typedef __bf16 bf16x4 __attribute__((ext_vector_type(4)));
typedef float floatx4 __attribute__((ext_vector_type(4)));

// ---------------------------------------------------------------- helpers
__device__ __forceinline__ void async16(const bf16_t* g, bf16_t* l) {
  __builtin_amdgcn_global_load_lds(
      (const __attribute__((address_space(1))) unsigned int*)g,
      (__attribute__((address_space(3))) unsigned int*)l, 16, 0, 0);
}

// Barrier that drains ONLY lgkmcnt (LDS) — leaves prefetch global loads
// in flight across the barrier (compiler's __syncthreads drains vmcnt(0)).
__device__ __forceinline__ void barrier_lds() {
  asm volatile("s_waitcnt lgkmcnt(0)\n\ts_barrier" ::: "memory");
}

__device__ __forceinline__ float siluf(float x) { return x / (1.f + __expf(-x)); }

#define MFMA16(a, b, c) __builtin_amdgcn_mfma_f32_16x16x32_bf16(a, b, c, 0, 0, 0)
#define WAITV(n) asm volatile("s_waitcnt vmcnt(" #n ")" ::: "memory")
#define SBAR() asm volatile("s_barrier" ::: "memory")

// ---------------------------------------------------------------- fp32 -> bf16
__global__ __launch_bounds__(256) void k_cvt(const float* __restrict__ in,
                                             bf16_t* __restrict__ out, int n4) {
  int i = blockIdx.x * 256 + threadIdx.x;
  if (i >= n4) return;
  const float4 f = ((const float4*)in)[i];
  bf16x4 r;
  r[0] = (bf16_t)f.x; r[1] = (bf16_t)f.y; r[2] = (bf16_t)f.z; r[3] = (bf16_t)f.w;
  ((bf16x4*)out)[i] = r;
}

// W_b rows 0..31, W_a rows 32..63, zeros 64..127
__global__ __launch_bounds__(256) void k_build_wba(const float* __restrict__ wb,
                                                   const float* __restrict__ wa,
                                                   bf16_t* __restrict__ out) {
  int i = blockIdx.x * 256 + threadIdx.x;
  int e = i * 4;
  int row = e >> 11;
  int col = e & 2047;
  float4 f = make_float4(0.f, 0.f, 0.f, 0.f);
  if (row < 32)      f = *(const float4*)&wb[row * 2048 + col];
  else if (row < 64) f = *(const float4*)&wa[(row - 32) * 2048 + col];
  bf16x4 r;
  r[0] = (bf16_t)f.x; r[1] = (bf16_t)f.y; r[2] = (bf16_t)f.z; r[3] = (bf16_t)f.w;
  *(bf16x4*)&out[e] = r;
}

// ---------------------------------------------------------------- GEMM (m97-style)
// Kept for the small N=128 (ba) GEMM.
template<bool OUT_BF16>
__global__ __launch_bounds__(256) void gemm_bt(const bf16_t* __restrict__ A,
                                               const bf16_t* __restrict__ B,
                                               void* __restrict__ Cout,
                                               int M, int N, int K) {
  __shared__ __align__(16) bf16_t As[4096];
  __shared__ __align__(16) bf16_t Bs[4096];
  const int tid  = threadIdx.x;
  const int lane = tid & 63;
  const int wave = tid >> 6;
  const int quad = lane >> 4;
  const int l16  = lane & 15;
  const int wr   = (wave >> 1) * 64;
  const int wc   = (wave & 1) * 64;
  const int m0   = blockIdx.y * 128;
  const int n0   = blockIdx.x * 128;
  const int ra   = tid >> 2;
  const int ca   = (tid & 3) * 8;

  const bf16_t* gA = A + (size_t)(m0 + ra) * K + ca;
  const bf16_t* gB = B + (size_t)(n0 + ra) * K + ca;
  bf16_t* lA = &As[tid * 8];
  bf16_t* lB = &Bs[tid * 8];

  floatx4 acc[4][4] = {};

  for (int k0 = 0; k0 < K; k0 += 32) {
    __syncthreads();
    async16(gA + k0, lA);
    async16(gA + k0 + (size_t)64 * K, lA + 2048);
    async16(gB + k0, lB);
    async16(gB + k0 + (size_t)64 * K, lB + 2048);
    __syncthreads();
    bf16x8 af[4], bfr[4];
#pragma unroll
    for (int i = 0; i < 4; ++i) {
      af[i]  = *(const bf16x8*)&As[(wr + i * 16 + l16) * 32 + quad * 8];
      bfr[i] = *(const bf16x8*)&Bs[(wc + i * 16 + l16) * 32 + quad * 8];
    }
#pragma unroll
    for (int mi = 0; mi < 4; ++mi)
#pragma unroll
      for (int ni = 0; ni < 4; ++ni)
        acc[mi][ni] = MFMA16(af[mi], bfr[ni], acc[mi][ni]);
  }

#pragma unroll
  for (int mi = 0; mi < 4; ++mi) {
#pragma unroll
    for (int ni = 0; ni < 4; ++ni) {
      const int row = m0 + wr + mi * 16 + quad * 4;
      const int col = n0 + wc + ni * 16 + l16;
#pragma unroll
      for (int r = 0; r < 4; ++r) {
        if (OUT_BF16)
          ((bf16_t*)Cout)[(size_t)(row + r) * N + col] = (bf16_t)acc[mi][ni][r];
        else
          ((float*)Cout)[(size_t)(row + r) * N + col] = acc[mi][ni][r];
      }
    }
  }
}

// ---------------------------------------------------------------- 8-phase 256x256 GEMM (BK=64)
// Full T-stack: T1 2D-patch XCD map, T2 LDS swizzle, T3 8-phase, T4 counted
// vmcnt, T5 setprio. 512 thr = 8 waves (2M x 4N), per-wave C = 128x64.
// LDS: 2 dbuf x (A[256][64] + B[256][64]) = 128 KB. K-tile X in buf X&1.
// Per K-tile, 4 phases = C-quadrants; 16 MFMA/phase, 1 half-tile staged/phase:
//   P1: stage A(X+1).lo ; lgkmcnt(8) throttle (12 ds_reads this phase)
//   P2: stage A(X+1).hi
//   P3: stage B(X+2).lo
//   P4: stage B(X+2).hi ; MFMA ; WAITV(4) AFTER MFMA (drain overlaps compute,
//       still before the barrier gating next-tile reads — per-wave vmcnt +
//       barrier preserve the guarantee)  [R8: drain-before-MFMA serialized]
// Stage sources are RUNNING pointers (pAs/pBs += 64/tile) — no per-stage
// 64-bit recompute (R8: VALUBusy 21%).
// Swizzle: LDS[row][c8] = G[row][c8 ^ (row&7)]; source pre-swizzled (rule #21).
// SPLIT-STORE epilogue routes tiles to C0 (n0 < NSPLIT) or C1.
__global__ __launch_bounds__(512, 1) void gemm8p(const bf16_t* __restrict__ A,
                                                 const bf16_t* __restrict__ B,
                                                 bf16_t* __restrict__ C0,
                                                 bf16_t* __restrict__ C1,
                                                 int M, int N, int K, int NSPLIT) {
  extern __shared__ __align__(16) bf16_t sm[];
  const int tid  = threadIdx.x;
  const int lane = tid & 63;
  const int wave = tid >> 6;   // 0..7
  const int quad = lane >> 4;
  const int l16  = lane & 15;
  const int wm   = wave >> 2;  // M half (128 rows)
  const int wn   = wave & 3;   // N quarter (64 cols)

  // T1: XCD mapping. For the 48x16 grid: 2D patches — XCD owns 8m x 12n
  // tiles (A 8MB + B 12MB L2-fill per XCD vs 2MB + 48MB with the 1-D row
  // swizzle; R8 FETCH was 410MB ≈ 8 XCDs x full-B streams). Fallback: 1-D.
  const int gx  = (int)gridDim.x;
  const int gy  = (int)gridDim.y;
  const int id  = (int)blockIdx.y * gx + (int)blockIdx.x;
  int m0, n0;
  if (gx == 48 && gy == 16) {
    const int x8 = id & 7, j = id >> 3;          // j in 0..95
    m0 = ((x8 & 1) * 8 + (j & 7)) * 256;         // m-tile 0..15
    n0 = ((x8 >> 1) * 12 + (j >> 3)) * 256;      // n-tile 0..47
  } else {
    const int nwg = gx * gy, cpx = nwg >> 3;
    const int sw = (id & 7) * cpx + (id >> 3);
    m0 = (sw / gx) * 256;
    n0 = (sw % gx) * 256;
  }

  // staging: one half-tile = [128][64] bf16 = 16KB = 512 thr x 2 x 16B.
  const int rowg   = tid >> 3;
  const int colsrc = (tid & 7) ^ (rowg & 7);
  const bf16_t* gAs = A + (size_t)(m0 + rowg) * K + colsrc * 8;
  const bf16_t* gBs = B + (size_t)(n0 + rowg) * K + colsrc * 8;
  bf16_t* lds0 = sm + tid * 8;
  const size_t rowK = (size_t)K;
  const size_t H64  = rowK * 64;   // +64 rows (second async16 of a half-tile)
  const size_t H128 = rowK * 128;  // +128 rows (half-tile 1)

#define STG_A8(u, kt, ht) {                                     \
    bf16_t* la = lds0 + (u) * 32768 + (ht) * 8192;              \
    const bf16_t* ga = gAs + (size_t)(ht) * H128 + (kt) * 64;   \
    async16(ga, la); async16(ga + H64, la + 4096); }
#define STG_B8(u, kt, ht) {                                     \
    bf16_t* lb = lds0 + (u) * 32768 + 16384 + (ht) * 8192;      \
    const bf16_t* gb = gBs + (size_t)(ht) * H128 + (kt) * 64;   \
    async16(gb, lb); async16(gb + H64, lb + 4096); }

  // fragment read constants (row&7 == l16&7 for all frag rows)
  const int x7  = l16 & 7;
  const int cA0 = ((quad + 0) ^ x7) * 8;  // kk=0 swizzled 8-elem slot
  const int cA1 = ((quad + 4) ^ x7) * 8;  // kk=1
  const int eA0 = (wm * 128 + l16) * 64;
  const int eB0 = 16384 + (wn * 64 + l16) * 64;

  floatx4 acc[8][4] = {};
  const int KT = K >> 6;  // BK=64; caller guarantees K%64==0, KT>=3

  // ---- prologue: A0.lo A0.hi B0.lo B0.hi B1.lo B1.hi (12 loads)
  STG_A8(0, 0, 0); STG_A8(0, 0, 1);
  STG_B8(0, 0, 0); STG_B8(0, 0, 1);
  STG_B8(1, 1, 0); STG_B8(1, 1, 1);
  WAITV(4);
  SBAR();

  // running stage-source pointers: pAs -> A(X+1), pBs -> B(X+2)
  const bf16_t* pAs = gAs + 64;
  const bf16_t* pBs = gBs + 128;

  bf16x8 af[4][2], bn0[2][2], bn1[2][2];
  for (int X = 0; X < KT; ++X) {
    const int c = X & 1;
    const bf16_t* sb = sm + c * 32768;
    bf16_t* dA = lds0 + (c ^ 1) * 32768;          // A(X+1) dest buf
    bf16_t* dB = lds0 + c * 32768 + 16384;        // B(X+2) dest buf
    const bool stgA = (X + 1 < KT);
    const bool stgB = (X + 2 < KT);

    // ---- P1: (mh0, nh0); read A-mh0 (8) + B-nh0 (4); stage A(X+1).lo
#pragma unroll
    for (int i = 0; i < 4; ++i) {
      af[i][0] = *(const bf16x8*)&sb[eA0 + i * 1024 + cA0];
      af[i][1] = *(const bf16x8*)&sb[eA0 + i * 1024 + cA1];
    }
#pragma unroll
    for (int j = 0; j < 2; ++j) {
      bn0[j][0] = *(const bf16x8*)&sb[eB0 + j * 1024 + cA0];
      bn0[j][1] = *(const bf16x8*)&sb[eB0 + j * 1024 + cA1];
    }
    if (stgA) { async16(pAs, dA); async16(pAs + H64, dA + 4096); }
    asm volatile("s_waitcnt lgkmcnt(8)" ::: "memory");  // throttle 12-read burst
    SBAR();
    __builtin_amdgcn_s_setprio(1);
#pragma unroll
    for (int i = 0; i < 4; ++i)
#pragma unroll
      for (int j = 0; j < 2; ++j) {
        acc[i][j] = MFMA16(af[i][0], bn0[j][0], acc[i][j]);
        acc[i][j] = MFMA16(af[i][1], bn0[j][1], acc[i][j]);
      }
    __builtin_amdgcn_s_setprio(0);
    SBAR();

    // ---- P2: (mh0, nh1); read B-nh1 (4); stage A(X+1).hi
#pragma unroll
    for (int j = 0; j < 2; ++j) {
      bn1[j][0] = *(const bf16x8*)&sb[eB0 + (2 + j) * 1024 + cA0];
      bn1[j][1] = *(const bf16x8*)&sb[eB0 + (2 + j) * 1024 + cA1];
    }
    if (stgA) {
      const bf16_t* g = pAs + H128;
      async16(g, dA + 8192); async16(g + H64, dA + 8192 + 4096);
    }
    SBAR();
    __builtin_amdgcn_s_setprio(1);
#pragma unroll
    for (int i = 0; i < 4; ++i)
#pragma unroll
      for (int j = 0; j < 2; ++j) {
        acc[i][2 + j] = MFMA16(af[i][0], bn1[j][0], acc[i][2 + j]);
        acc[i][2 + j] = MFMA16(af[i][1], bn1[j][1], acc[i][2 + j]);
      }
    __builtin_amdgcn_s_setprio(0);
    SBAR();

    // ---- P3: (mh1, nh0); read A-mh1 (8); stage B(X+2).lo
#pragma unroll
    for (int i = 0; i < 4; ++i) {
      af[i][0] = *(const bf16x8*)&sb[eA0 + (4 + i) * 1024 + cA0];
      af[i][1] = *(const bf16x8*)&sb[eA0 + (4 + i) * 1024 + cA1];
    }
    if (stgB) { async16(pBs, dB); async16(pBs + H64, dB + 4096); }
    SBAR();
    __builtin_amdgcn_s_setprio(1);
#pragma unroll
    for (int i = 0; i < 4; ++i)
#pragma unroll
      for (int j = 0; j < 2; ++j) {
        acc[4 + i][j] = MFMA16(af[i][0], bn0[j][0], acc[4 + i][j]);
        acc[4 + i][j] = MFMA16(af[i][1], bn0[j][1], acc[4 + i][j]);
      }
    __builtin_amdgcn_s_setprio(0);
    SBAR();

    // ---- P4: (mh1, nh1); stage B(X+2).hi; MFMA; counted drain AFTER MFMA
    if (stgB) {
      const bf16_t* g = pBs + H128;
      async16(g, dB + 8192); async16(g + H64, dB + 8192 + 4096);
    }
    SBAR();
    __builtin_amdgcn_s_setprio(1);
#pragma unroll
    for (int i = 0; i < 4; ++i)
#pragma unroll
      for (int j = 0; j < 2; ++j) {
        acc[4 + i][2 + j] = MFMA16(af[i][0], bn1[j][0], acc[4 + i][2 + j]);
        acc[4 + i][2 + j] = MFMA16(af[i][1], bn1[j][1], acc[4 + i][2 + j]);
      }
    __builtin_amdgcn_s_setprio(0);
    if (stgB) WAITV(4);
    else      WAITV(0);
    SBAR();

    pAs += 64; pBs += 64;
  }
#undef STG_A8
#undef STG_B8

  // ---- split-store epilogue (proven C/D mapping)
  const bool lo = (n0 < NSPLIT);
  bf16_t* Cb = lo ? C0 : C1;
  const int pitch = lo ? NSPLIT : (N - NSPLIT);
  const int ncol0 = lo ? n0 : (n0 - NSPLIT);
#pragma unroll
  for (int mi = 0; mi < 8; ++mi) {
#pragma unroll
    for (int ni = 0; ni < 4; ++ni) {
      const int row = m0 + wm * 128 + mi * 16 + quad * 4;
      const int col = ncol0 + wn * 64 + ni * 16 + l16;
#pragma unroll
      for (int r = 0; r < 4; ++r)
        Cb[(size_t)(row + r) * pitch + col] = (bf16_t)acc[mi][ni][r];
    }
  }
}

// ---------------------------------------------------------------- big-tile deep-pipelined GEMM
// MH=1: BM=128 (N=2048 out-GEMM: grid (8,32)=256 blocks -> full GPU),
// 2-phase, per-wave loads/K-tile = 3 -> vmcnt 6/3/0; ring 4 x 24KB = 96KB LDS.
template<int MH, bool OUT_BF16>
__global__ __launch_bounds__(512, 1) void gemm_big(const bf16_t* __restrict__ A,
                                                   const bf16_t* __restrict__ B,
                                                   void* __restrict__ Cout,
                                                   int M, int N, int K) {
  extern __shared__ __align__(16) bf16_t sm[];
  constexpr int BM    = MH * 128;
  constexpr int MFRAG = MH * 4;
  constexpr int HF    = MFRAG / 2;
  constexpr int BUFE  = MH * 4096 + 8192;  // elems per ring buffer (A + B)
  const int tid  = threadIdx.x;
  const int lane = tid & 63;
  const int wave = tid >> 6;   // 0..7
  const int quad = lane >> 4;
  const int l16  = lane & 15;
  const int wm   = wave >> 2;  // 0..1  M half
  const int wn   = wave & 3;   // 0..3  N quarter (64 cols)

  // bijective XCD swizzle (caller guarantees nwg % 8 == 0)
  const int gx  = (int)gridDim.x;
  const int nwg = gx * (int)gridDim.y;
  const int id  = (int)blockIdx.y * gx + (int)blockIdx.x;
  const int cpx = nwg >> 3;
  const int sw  = (id & 7) * cpx + (id >> 3);
  const int m0  = (sw / gx) * BM;
  const int n0  = (sw % gx) * 256;

  // ---- staging addresses (each issue: 64 lanes x 16B = 16 rows x 64B)
  const int lr    = lane >> 2;                       // row within issue
  const int lslot = (lane & 3) ^ ((lane >> 3) & 3);  // pre-swizzled 16B slot
  const bf16_t* gA = A + (size_t)(m0 + wave * (MH * 16) + lr) * K + lslot * 8;
  const bf16_t* gB = B + (size_t)(n0 + wave * 32 + lr) * K + lslot * 8;
  const int ldsA0 = wave * (MH * 512) + lane * 8;
  const int ldsB0 = MH * 4096 + wave * 1024 + lane * 8;

#define STG_A(u, kt) {                                          \
    bf16_t* la = sm + (u) * BUFE + ldsA0;                       \
    const bf16_t* ga = gA + (size_t)(kt) * 32;                  \
    async16(ga, la);                                            \
    if constexpr (MH == 2) async16(ga + (size_t)16 * K, la + 512); }
#define STG_B(u, kt) {                                          \
    bf16_t* lb = sm + (u) * BUFE + ldsB0;                       \
    const bf16_t* gb = gB + (size_t)(kt) * 32;                  \
    async16(gb, lb);                                            \
    async16(gb + (size_t)16 * K, lb + 512); }

  int offA[MFRAG], offB[4];
#pragma unroll
  for (int i = 0; i < MFRAG; ++i) {
    int ra = wm * (MFRAG * 16) + i * 16 + l16;
    offA[i] = (ra * 32 + quad * 8) ^ (((ra >> 1) & 3) << 3);
  }
#pragma unroll
  for (int i = 0; i < 4; ++i) {
    int rb = wn * 64 + i * 16 + l16;
    offB[i] = MH * 4096 + ((rb * 32 + quad * 8) ^ (((rb >> 1) & 3) << 3));
  }

  floatx4 acc[MFRAG][4] = {};
  const int KT = K >> 5;  // caller guarantees KT >= 4

  STG_A(0, 0); STG_B(0, 0);
  STG_A(1, 1); STG_B(1, 1);
  STG_A(2, 2); STG_B(2, 2);
  if constexpr (MH == 2) WAITV(8); else WAITV(6);
  SBAR();

  for (int U = 0; U < KT; ++U) {
    const int bu = U & 3;
    const bf16_t* sb = sm + bu * BUFE;
    const int un = U + 3;
    const int tu = un & 3;
    bf16x8 af[HF], bfr[4];

    // ---- phase 0: M lower half; stage A(U+3)
#pragma unroll
    for (int i = 0; i < HF; ++i) af[i] = *(const bf16x8*)&sb[offA[i]];
#pragma unroll
    for (int i = 0; i < 4; ++i) bfr[i] = *(const bf16x8*)&sb[offB[i]];
    if (un < KT) STG_A(tu, un);
    SBAR();
    __builtin_amdgcn_s_setprio(1);
#pragma unroll
    for (int mi = 0; mi < HF; ++mi)
#pragma unroll
      for (int ni = 0; ni < 4; ++ni)
        acc[mi][ni] = MFMA16(af[mi], bfr[ni], acc[mi][ni]);
    __builtin_amdgcn_s_setprio(0);
    SBAR();

    // ---- phase 1: M upper half; stage B(U+3); counted vmcnt
#pragma unroll
    for (int i = 0; i < HF; ++i) af[i] = *(const bf16x8*)&sb[offA[HF + i]];
    if (un < KT) STG_B(tu, un);
    if (un < KT)         { if constexpr (MH == 2) WAITV(8); else WAITV(6); }
    else if (U + 2 < KT) { if constexpr (MH == 2) WAITV(4); else WAITV(3); }
    else                 WAITV(0);
    SBAR();
    __builtin_amdgcn_s_setprio(1);
#pragma unroll
    for (int mi = 0; mi < HF; ++mi)
#pragma unroll
      for (int ni = 0; ni < 4; ++ni)
        acc[HF + mi][ni] = MFMA16(af[mi], bfr[ni], acc[HF + mi][ni]);
    __builtin_amdgcn_s_setprio(0);
    SBAR();
  }
#undef STG_A
#undef STG_B

#pragma unroll
  for (int mi = 0; mi < MFRAG; ++mi) {
#pragma unroll
    for (int ni = 0; ni < 4; ++ni) {
      const int row = m0 + wm * (MFRAG * 16) + mi * 16 + quad * 4;
      const int col = n0 + wn * 64 + ni * 16 + l16;
#pragma unroll
      for (int r = 0; r < 4; ++r) {
        if (OUT_BF16)
          ((bf16_t*)Cout)[(size_t)(row + r) * N + col] = (bf16_t)acc[mi][ni][r];
        else
          ((float*)Cout)[(size_t)(row + r) * N + col] = acc[mi][ni][r];
      }
    }
  }
}

// ---------------------------------------------------------------- beta / g ([h][t] layout)
__global__ __launch_bounds__(256) void k_betag(const float* __restrict__ cba,
                                               const float* __restrict__ A_log,
                                               const float* __restrict__ dtb,
                                               float* __restrict__ beta_t,
                                               float* __restrict__ g_t) {
  int i = blockIdx.x * 256 + threadIdx.x;  // T*32
  int t = i >> 5, h = i & 31;
  float b = cba[t * 128 + h];
  float a = cba[t * 128 + 32 + h];
  beta_t[h * 4096 + t] = 1.f / (1.f + __expf(-b));
  float x = a + dtb[h];
  float sp = (x > 20.f) ? x : log1pf(__expf(x));
  g_t[h * 4096 + t] = -__expf(A_log[h]) * sp;
}

// ---------------------------------------------------------------- conv4 + silu + l2norm
__global__ __launch_bounds__(64) void k_conv(const bf16_t* __restrict__ mixed,
                                             const float* __restrict__ cw,
                                             bf16_t* __restrict__ qo,
                                             bf16_t* __restrict__ ko,
                                             bf16_t* __restrict__ vo) {
  const int grp = blockIdx.x;
  const int t0 = blockIdx.y * 8;
  const int l = threadIdx.x;
  const int c0 = grp * 128 + l;
  const int c1 = c0 + 64;
  const float4 w0 = *(const float4*)&cw[c0 * 4];
  const float4 w1 = *(const float4*)&cw[c1 * 4];
  float h0[3], h1[3];
#pragma unroll
  for (int j = 0; j < 3; ++j) {
    int tt = t0 - 3 + j;
    h0[j] = (tt >= 0) ? (float)mixed[(size_t)tt * 8192 + c0] : 0.f;
    h1[j] = (tt >= 0) ? (float)mixed[(size_t)tt * 8192 + c1] : 0.f;
  }
#pragma unroll
  for (int i = 0; i < 8; ++i) {
    const int t = t0 + i;
    float x0 = (float)mixed[(size_t)t * 8192 + c0];
    float x1 = (float)mixed[(size_t)t * 8192 + c1];
    float a0 = w0.x * h0[0] + w0.y * h0[1] + w0.z * h0[2] + w0.w * x0;
    float a1 = w1.x * h1[0] + w1.y * h1[1] + w1.z * h1[2] + w1.w * x1;
    h0[0] = h0[1]; h0[1] = h0[2]; h0[2] = x0;
    h1[0] = h1[1]; h1[1] = h1[2]; h1[2] = x1;
    float v0 = siluf(a0), v1 = siluf(a1);
    if (grp < 32) {
      float s = v0 * v0 + v1 * v1;
#pragma unroll
      for (int m = 1; m < 64; m <<= 1) s += __shfl_xor(s, m);
      float r = rsqrtf(s + 1e-6f);
      if (grp < 16) {
        bf16_t* q = qo + ((size_t)t * 16 + grp) * 128;
        q[l]      = (bf16_t)(v0 * r * 0.08838834764831845f);  // DK^-0.5 folded
        q[l + 64] = (bf16_t)(v1 * r * 0.08838834764831845f);
      } else {
        bf16_t* k = ko + ((size_t)t * 16 + grp - 16) * 128;
        k[l]      = (bf16_t)(v0 * r);
        k[l + 64] = (bf16_t)(v1 * r);
      }
    } else {
      bf16_t* v = vo + ((size_t)t * 32 + grp - 32) * 128;
      v[l]      = (bf16_t)v0;
      v[l + 64] = (bf16_t)v1;
    }
  }
}

// ---------------------------------------------------------------- k_prep
__global__ __launch_bounds__(256, 2) void k_prep(
    const bf16_t* __restrict__ qg, const bf16_t* __restrict__ kg,
    const bf16_t* __restrict__ vg,
    const float* __restrict__ bb_t, const float* __restrict__ gb_t,
    bf16_t* __restrict__ Vt, bf16_t* __restrict__ Wlo, bf16_t* __restrict__ Whi,
    bf16_t* __restrict__ Mout, bf16_t* __restrict__ kt, float* __restrict__ smalls) {
  const int c = blockIdx.x >> 5;
  const int h = blockIdx.x & 31;
  const int kh = h >> 1;
  const int t0 = c * 64;
  const int tid = threadIdx.x, lane = tid & 63, wave = tid >> 6;
  const int quad = lane >> 4, l16 = lane & 15;

  __shared__ __align__(16) bf16_t lsKQ[2][64][136];
  __shared__ float lsC[64][68];
  __shared__ float lsG[64], lsA[64], lsSc[64], lsBeta[64];

  {
    const int r = tid >> 2, s0 = (tid & 3) * 32;
    const bf16_t* kr = kg + ((size_t)(t0 + r) * 16 + kh) * 128 + s0;
    const bf16_t* qr = qg + ((size_t)(t0 + r) * 16 + kh) * 128 + s0;
#pragma unroll
    for (int j = 0; j < 4; ++j) {
      *(uint4*)&lsKQ[0][r][s0 + j * 8] = *(const uint4*)&kr[j * 8];
      *(uint4*)&lsKQ[1][r][s0 + j * 8] = *(const uint4*)&qr[j * 8];
    }
  }
  if (wave == 0) {
    float gv = gb_t[(size_t)h * 4096 + t0 + lane];
#pragma unroll
    for (int off = 1; off < 64; off <<= 1) {
      float n = __shfl_up(gv, off);
      if (lane >= off) gv += n;
    }
    float GL = __shfl(gv, 63);
    lsG[lane] = gv;
    lsA[lane] = __expf(gv);
    lsSc[lane] = __expf(GL - gv);
    lsBeta[lane] = bb_t[(size_t)h * 4096 + t0 + lane];
  }
  __syncthreads();

  const int mr = (wave >> 1) * 32, nr = (wave & 1) * 32;
  floatx4 ak[2][2] = {}, aq[2][2] = {};
  if (wave != 1) {
#pragma unroll
    for (int ks = 0; ks < 4; ++ks) {
      bf16x8 yf[2], xk[2], xq[2];
#pragma unroll
      for (int i = 0; i < 2; ++i) {
        yf[i] = *(const bf16x8*)&lsKQ[0][nr + i * 16 + l16][ks * 32 + quad * 8];
        xk[i] = *(const bf16x8*)&lsKQ[0][mr + i * 16 + l16][ks * 32 + quad * 8];
        xq[i] = *(const bf16x8*)&lsKQ[1][mr + i * 16 + l16][ks * 32 + quad * 8];
      }
#pragma unroll
      for (int i = 0; i < 2; ++i)
#pragma unroll
        for (int j = 0; j < 2; ++j) {
          ak[i][j] = MFMA16(xk[i], yf[j], ak[i][j]);
          aq[i][j] = MFMA16(xq[i], yf[j], aq[i][j]);
        }
    }
  }
  bf16_t* Mb = Mout + (size_t)(h * 64 + c) * 4096;
#pragma unroll
  for (int i = 0; i < 2; ++i)
#pragma unroll
    for (int j = 0; j < 2; ++j)
#pragma unroll
      for (int r = 0; r < 4; ++r) {
        int t = mr + i * 16 + quad * 4 + r;
        int s = nr + j * 16 + l16;
        float e = __expf(lsG[t] - lsG[s]);
        float cv = (s < t) ? lsBeta[t] * e * ak[i][j][r] : 0.f;
        float mv = (s <= t) ? e * aq[i][j][r] : 0.f;
        if (wave != 1) lsC[t][s] = cv;
        Mb[t * 64 + s] = (bf16_t)mv;
      }
  __syncthreads();

  // forward substitution: thread <-> column. cols 0..127: V, 128..255: W-rhs
  const int col = tid & 127;
  const bool isW = tid >= 128;
  float vals[64];
#pragma unroll
  for (int t = 0; t < 64; ++t) {
    float b;
    if (!isW) b = (float)vg[((size_t)(t0 + t) * 32 + h) * 128 + col];
    else      b = lsA[t] * (float)lsKQ[0][t][col];
    vals[t] = lsBeta[t] * b;
  }
#pragma unroll
  for (int t = 1; t < 64; ++t) {
    float acc = vals[t];
#pragma unroll
    for (int s4 = 0; s4 <= (t - 1) >> 2; ++s4) {
      float4 cv = *(const float4*)&lsC[t][s4 * 4];
      acc -= cv.x * vals[s4 * 4 + 0];
      acc -= cv.y * vals[s4 * 4 + 1];
      acc -= cv.z * vals[s4 * 4 + 2];
      acc -= cv.w * vals[s4 * 4 + 3];
    }
    vals[t] = acc;
  }

  // V columns: direct transposed write (VtT[dv][t], contiguous in t)
  if (!isW) {
    bf16_t* vd = Vt + (size_t)(h * 64 + c) * 8192 + (size_t)col * 64;
#pragma unroll
    for (int j = 0; j < 16; ++j) {
      bf16x4 p;
      p[0] = (bf16_t)vals[j * 4 + 0];
      p[1] = (bf16_t)vals[j * 4 + 1];
      p[2] = (bf16_t)vals[j * 4 + 2];
      p[3] = (bf16_t)vals[j * 4 + 3];
      *(bf16x4*)&vd[j * 4] = p;
    }
  } else {
#pragma unroll
    for (int t = 0; t < 64; ++t) vals[t] = -vals[t];  // W' = -W
  }

  // K^T for the chain
  if ((h & 1) == 0) {
    const int dk = tid >> 1, sh = (tid & 1) * 32;
    bf16_t* kd = kt + (size_t)(c * 16 + kh) * 8192 + (size_t)dk * 64 + sh;
#pragma unroll
    for (int j4 = 0; j4 < 4; ++j4) {
      bf16x8 v;
#pragma unroll
      for (int e = 0; e < 8; ++e) v[e] = lsKQ[0][sh + j4 * 8 + e][dk];
      *(bf16x8*)&kd[j4 * 8] = v;
    }
  }
  if (tid < 64) {
    float* sm = smalls + (size_t)(h * 64 + c) * 128;
    sm[tid] = lsA[tid];
    sm[64 + tid] = lsSc[tid];
  }
  __syncthreads();

  // transpose W half via LDS (overlay lsKQ), pitch 272
  bf16_t* lsT = &lsKQ[0][0][0];
  if (isW) {
#pragma unroll
    for (int t = 0; t < 64; ++t) lsT[t * 272 + tid] = (bf16_t)vals[t];
  }
  __syncthreads();

  // cooperative vectorized W' write: [t][dk 128]
  {
    const int r = tid >> 2, part = tid & 3;
    const bf16_t* src = &lsT[r * 272 + 128 + part * 32];
    bf16_t* Wb = (h < 16 ? Wlo : Whi) + (size_t)((h & 15) * 64 + c) * 8192 + r * 128 + part * 32;
#pragma unroll
    for (int j = 0; j < 4; ++j)
      *(uint4*)&Wb[j * 8] = *(const uint4*)&src[j * 8];
  }
}

// ---------------------------------------------------------------- k_chain (4-wave, dv-eighth)
// grid = 256: blockIdx = q*32 + h, q = dv-eighth (16 cols). q*32 ≡ 0 mod 8,
// so a head's 8 eighth-blocks land on the SAME XCD -> shared L2 for the
// W/Q/K/M streams all eight read. ALL 256 CUs active. 256 threads = 4 waves
// (1/SIMD; lockstep multi-wave REGRESSED R2; paired-group shared-barrier
// variant REGRESSED R7 — barrier forces groups into phase, no offset).
// Per chunk: X = Vt + W'.S ; o = A*(Q.S) + M.X ; S' = aL*S + K^T.(sc*X)
// S^T slice [dv 16][dk 128] lives in lsS[16][136].
__global__ __launch_bounds__(256, 1) void k_chain(
    const bf16_t* __restrict__ qg, const bf16_t* __restrict__ VtT,
    const bf16_t* __restrict__ Wlo, const bf16_t* __restrict__ Whi,
    const bf16_t* __restrict__ Mg, const bf16_t* __restrict__ ktg,
    const float* __restrict__ smalls, bf16_t* __restrict__ o) {
  const int h = blockIdx.x & 31;
  const int dv0 = (blockIdx.x >> 5) * 16;
  const int kh = h >> 1;
  const int tid = threadIdx.x, lane = tid & 63, wave = tid >> 6;
  const int quad = lane >> 4, l16 = lane & 15;
  const int trow = wave * 16 + quad * 4;

  __shared__ __align__(16) bf16_t lsXT[16][72];
  __shared__ __align__(16) bf16_t lsXbT[16][72];
  __shared__ __align__(16) bf16_t lsS[16][136];

  const bf16_t* Wbase = (h < 16 ? Wlo : Whi) + (size_t)(h & 15) * 64 * 8192;
  const bf16_t* Vbase = VtT + (size_t)h * 64 * 8192;
  const bf16_t* Mbase = Mg + (size_t)h * 64 * 4096;
  const float*  Sbase = smalls + (size_t)h * 64 * 128;

  // running per-wave pointers (advanced by constant strides per chunk)
  const bf16_t* pW = Wbase + (size_t)(wave * 16 + l16) * 128 + quad * 8;
  const bf16_t* pQ = qg + ((size_t)(wave * 16 + l16) * 16 + kh) * 128 + quad * 8;
  const bf16_t* pK = ktg + (size_t)kh * 8192 + (size_t)(wave * 16 + l16) * 64 + quad * 8;
  const bf16_t* pM = Mbase + (size_t)(wave * 16 + l16) * 64 + quad * 8;
  const bf16_t* pV = Vbase + (size_t)(dv0 + l16) * 64 + trow;
  const float*  pS = Sbase;

  floatx4 sacc[2] = {};
  for (int i = tid; i < 16 * 136; i += 256) (&lsS[0][0])[i] = (bf16_t)0.f;

  bf16x8 nW[4], nQ[4], nK[4], nM[2];
  bf16x4 nV;
  float4 nA, nSc;
  float nAL;
  {
#pragma unroll
    for (int ks = 0; ks < 4; ++ks) {
      nW[ks] = *(const bf16x8*)&pW[ks * 32];
      nQ[ks] = *(const bf16x8*)&pQ[ks * 32];
    }
    nK[0] = *(const bf16x8*)&pK[0];
    nK[1] = *(const bf16x8*)&pK[32];
    nK[2] = *(const bf16x8*)&pK[4096];
    nK[3] = *(const bf16x8*)&pK[4096 + 32];
    nM[0] = *(const bf16x8*)&pM[0];
    nM[1] = *(const bf16x8*)&pM[32];
    nV = *(const bf16x4*)&pV[0];
    nA  = *(const float4*)&pS[trow];
    nSc = *(const float4*)&pS[64 + trow];
    nAL = pS[63];
    pW += 8192; pQ += 131072; pK += 131072; pM += 4096; pV += 8192; pS += 128;
  }
  __syncthreads();

  for (int cc = 0; cc < 64; ++cc) {
    const int t0 = cc * 64;
    bf16x8 cW[4], cQ[4], cK[4], cM[2];
    float cV[4];
    float4 cA = nA, cSc = nSc;
    float cAL = nAL;
#pragma unroll
    for (int ks = 0; ks < 4; ++ks) { cW[ks] = nW[ks]; cQ[ks] = nQ[ks]; cK[ks] = nK[ks]; }
    cM[0] = nM[0]; cM[1] = nM[1];
#pragma unroll
    for (int r = 0; r < 4; ++r) cV[r] = (float)nV[r];

    if (cc + 1 < 64) {
#pragma unroll
      for (int ks = 0; ks < 4; ++ks) {
        nW[ks] = *(const bf16x8*)&pW[ks * 32];
        nQ[ks] = *(const bf16x8*)&pQ[ks * 32];
      }
      nK[0] = *(const bf16x8*)&pK[0];
      nK[1] = *(const bf16x8*)&pK[32];
      nK[2] = *(const bf16x8*)&pK[4096];
      nK[3] = *(const bf16x8*)&pK[4096 + 32];
      nM[0] = *(const bf16x8*)&pM[0];
      nM[1] = *(const bf16x8*)&pM[32];
      nV = *(const bf16x4*)&pV[0];
      nA  = *(const float4*)&pS[trow];
      nSc = *(const float4*)&pS[64 + trow];
      nAL = pS[63];
      pW += 8192; pQ += 131072; pK += 131072; pM += 4096; pV += 8192; pS += 128;
    }

    // ---- P0: X = Vt + W'.S  (bS kept in regs)
    bf16x8 bS[4];
#pragma unroll
    for (int ks = 0; ks < 4; ++ks)
      bS[ks] = *(const bf16x8*)&lsS[l16][ks * 32 + quad * 8];
    floatx4 xacc;
#pragma unroll
    for (int r = 0; r < 4; ++r) xacc[r] = cV[r];
#pragma unroll
    for (int ks = 0; ks < 4; ++ks)
      xacc = MFMA16(cW[ks], bS[ks], xacc);
    {
      bf16x4 px, pb;
#pragma unroll
      for (int r = 0; r < 4; ++r) {
        px[r] = (bf16_t)xacc[r];
        pb[r] = (bf16_t)(xacc[r] * ((const float*)&cSc)[r]);
      }
      *(bf16x4*)&lsXT[l16][trow] = px;
      *(bf16x4*)&lsXbT[l16][trow] = pb;
    }
    // ---- independent reg-only work (hides the ds_write drain before B1):
    floatx4 qacc = {};
#pragma unroll
    for (int ks = 0; ks < 4; ++ks)
      qacc = MFMA16(cQ[ks], bS[ks], qacc);
#pragma unroll
    for (int r = 0; r < 4; ++r) qacc[r] *= ((const float*)&cA)[r];
#pragma unroll
    for (int mh = 0; mh < 2; ++mh)
#pragma unroll
      for (int r = 0; r < 4; ++r) sacc[mh][r] *= cAL;
    barrier_lds();  // B1: X ready; all lsS reads done

    // ---- P1 (short): o += M.X ; store o
#pragma unroll
    for (int ks = 0; ks < 2; ++ks) {
      bf16x8 bX = *(const bf16x8*)&lsXT[l16][ks * 32 + quad * 8];
      qacc = MFMA16(cM[ks], bX, qacc);
    }
#pragma unroll
    for (int r = 0; r < 4; ++r)
      o[((size_t)(t0 + trow + r) * 32 + h) * 128 + dv0 + l16] = (bf16_t)qacc[r];

    // ---- S' = aL*S + K^T.(sc*X)
#pragma unroll
    for (int ks = 0; ks < 2; ++ks) {
      bf16x8 bXb = *(const bf16x8*)&lsXbT[l16][ks * 32 + quad * 8];
#pragma unroll
      for (int mh = 0; mh < 2; ++mh)
        sacc[mh] = MFMA16(cK[mh * 2 + ks], bXb, sacc[mh]);
    }
    // ---- P2: refresh bf16 state (safe: all lsS reads happened before B1)
#pragma unroll
    for (int mh = 0; mh < 2; ++mh) {
      bf16x4 ps;
#pragma unroll
      for (int r = 0; r < 4; ++r) ps[r] = (bf16_t)sacc[mh][r];
      *(bf16x4*)&lsS[l16][(wave + 4 * mh) * 16 + quad * 4] = ps;
    }
    barrier_lds();  // B2: S visible; lsXT/lsXbT reads done before next P0 write
  }
}

// ---------------------------------------------------------------- RMSNorm * silu(z)
__global__ __launch_bounds__(256) void k_gate(const bf16_t* __restrict__ o,
                                              const bf16_t* __restrict__ z,
                                              const float* __restrict__ nw,
                                              bf16_t* __restrict__ y) {
  const int row = blockIdx.x * 4 + (threadIdx.x >> 6);  // t*32+h
  const int l = threadIdx.x & 63;
  const bf16_t* orow = o + (size_t)row * 128;
  float o0 = (float)orow[l], o1 = (float)orow[l + 64];
  float s = o0 * o0 + o1 * o1;
#pragma unroll
  for (int m = 1; m < 64; m <<= 1) s += __shfl_xor(s, m);
  float r = rsqrtf(s * (1.f / 128.f) + 1e-6f);
  const bf16_t* zrow = z + (size_t)row * 128;
  float z0 = (float)zrow[l], z1 = (float)zrow[l + 64];
  bf16_t* yrow = y + (size_t)row * 128;
  yrow[l]      = (bf16_t)(o0 * r * nw[l] * siluf(z0));
  yrow[l + 64] = (bf16_t)(o1 * r * nw[l + 64] * siluf(z1));
}

// ---------------------------------------------------------------- launch
extern "C" void kernel_launch(void* const* d_in, const int* in_sizes, int n_in,
                              void* d_out, int out_size, void* d_ws, size_t ws_size,
                              hipStream_t stream) {
  const float* hidden = (const float*)d_in[0];
  const float* W_qkv  = (const float*)d_in[1];
  const float* W_z    = (const float*)d_in[2];
  const float* W_b    = (const float*)d_in[3];
  const float* W_a    = (const float*)d_in[4];
  const float* conv_w = (const float*)d_in[5];
  const float* dt_b   = (const float*)d_in[6];
  const float* A_log  = (const float*)d_in[7];
  const float* norm_w = (const float*)d_in[8];
  const float* W_out  = (const float*)d_in[9];
  float* out = (float*)d_out;

  static int gemm_attr_done = 0;
  if (!gemm_attr_done) {
    hipFuncSetAttribute(reinterpret_cast<const void*>(&gemm8p),
                        hipFuncAttributeMaxDynamicSharedMemorySize, 131072);
    hipFuncSetAttribute(reinterpret_cast<const void*>(&gemm_big<1, false>),
                        hipFuncAttributeMaxDynamicSharedMemorySize, 98304);
    gemm_attr_done = 1;
  }

  char* w = (char*)d_ws;
  const size_t MB = 1024 * 1024;
  bf16_t* hs    = (bf16_t*)(w + 0 * MB);     // 16MB; after ba-GEMM -> W_lo
  bf16_t* Wlo   = hs;
  bf16_t* wqkv  = (bf16_t*)(w + 16 * MB);    // 32MB; -> VtT (prep) -> ybuf (gate)
  bf16_t* Vtb   = wqkv;
  bf16_t* ybuf  = wqkv;
  bf16_t* wz    = (bf16_t*)(w + 48 * MB);    // 16MB; ADJACENT to wqkv -> one
                                             //   contiguous B [12288][2048];
                                             //   later -> W_hi
  bf16_t* Whi   = wz;
  bf16_t* wout  = (bf16_t*)(w + 64 * MB);    // 16MB (live till end)
  bf16_t* wba   = (bf16_t*)(w + 80 * MB);    // 0.5MB
  bf16_t* mixed = (bf16_t*)(w + 81 * MB);    // 64MB (qkv out); after conv:
  bf16_t* obuf  = mixed;                     //   [obuf bf16 32MB @81]
  bf16_t* Mbuf  = (bf16_t*)(w + 113 * MB);   //   [M 16MB @113]
  bf16_t* ktb   = (bf16_t*)(w + 129 * MB);   //   [K^T 16MB @129]
  bf16_t* zbuf  = (bf16_t*)(w + 145 * MB);   // 32MB
  float*  cba   = (float*)(w + 177 * MB);    // 2MB; after betag -> smalls (1MB)
  float*  smalls= cba;
  bf16_t* qb    = (bf16_t*)(w + 179 * MB);   // 16MB
  bf16_t* kb    = (bf16_t*)(w + 195 * MB);   // 16MB
  bf16_t* vb    = (bf16_t*)(w + 211 * MB);   // 32MB
  float*  betab = (float*)(w + 243 * MB);    // 0.5MB [h][t]
  float*  gbuf  = (float*)(w + 243 * MB + 512 * 1024);  // 0.5MB [h][t]

  k_cvt<<<8192, 256, 0, stream>>>(hidden, hs, 2097152);
  k_cvt<<<16384, 256, 0, stream>>>(W_qkv, wqkv, 4194304);
  k_cvt<<<8192, 256, 0, stream>>>(W_z, wz, 2097152);
  k_cvt<<<8192, 256, 0, stream>>>(W_out, wout, 2097152);
  k_build_wba<<<256, 256, 0, stream>>>(W_b, W_a, wba);

  // ONE combined GEMM: B = [wqkv ; wz] (adjacent, 12288 rows), split-store
  // epilogue routes tiles to mixed (cols < 8192) or zbuf. grid %8==0.
  gemm8p<<<dim3(48, 16), 512, 131072, stream>>>(hs, wqkv, mixed, zbuf,
                                                4096, 12288, 2048, 8192);
  gemm_bt<false><<<dim3(1, 32), 256, 0, stream>>>(hs, wba, cba, 4096, 128, 2048);
  k_betag<<<512, 256, 0, stream>>>(cba, A_log, dt_b, betab, gbuf);

  k_conv<<<dim3(64, 512), 64, 0, stream>>>(mixed, conv_w, qb, kb, vb);

  k_prep<<<2048, 256, 0, stream>>>(qb, kb, vb, betab, gbuf,
                                   Vtb, Wlo, Whi, Mbuf, ktb, smalls);
  k_chain<<<256, 256, 0, stream>>>(qb, Vtb, Wlo, Whi, Mbuf, ktb, smalls, obuf);

  k_gate<<<32768, 256, 0, stream>>>(obuf, zbuf, norm_w, ybuf);
  // out-GEMM: 128x256 tile -> grid (8,32)=256 blocks (%8==0), full GPU. K=4096.
  gemm_big<1, false><<<dim3(8, 32), 512, 98304, stream>>>(ybuf, wout, out, 4096, 2048, 4096);
}